// Round 2
// baseline (5024.234 us; speedup 1.0000x reference)
//
#include <hip/hip_runtime.h>

#define D 128
#define NB 4
#define TILE_N 64

typedef unsigned short u16;

__device__ __forceinline__ float bf2f(u16 u) {
    union { unsigned int i; float f; } v; v.i = ((unsigned int)u) << 16; return v.f;
}
__device__ __forceinline__ u16 f2bf(float f) {
    union { float ff; unsigned int i; } v; v.ff = f;
    unsigned int r = v.i + 0x7fffu + ((v.i >> 16) & 1u);   // RNE
    return (u16)(r >> 16);
}

// -------------------- small utility kernels --------------------

__global__ __launch_bounds__(256) void degree_kernel(const int* __restrict__ dst,
                                                     float* __restrict__ cnt, int E) {
    int e = blockIdx.x * 256 + threadIdx.x;
    if (e < E) atomicAdd(&cnt[dst[e]], 1.0f);
}

__global__ __launch_bounds__(256) void inv_kernel(float* __restrict__ cnt, int n) {
    int i = blockIdx.x * 256 + threadIdx.x;
    if (i < n) cnt[i] = 1.0f / fmaxf(cnt[i], 1.0f);
}

__global__ __launch_bounds__(256) void gather_kernel(const int* __restrict__ entity,
                                                     const float* __restrict__ emb,
                                                     float* __restrict__ x0, int n) {
    int idx = blockIdx.x * 256 + threadIdx.x;  // float4 index over n*32
    if (idx >= n * 32) return;
    int row = idx >> 5, c = idx & 31;
    ((float4*)x0)[idx] = ((const float4*)emb)[(size_t)entity[row] * 32 + c];
}

// -------------------- primary: 5-matrix node GEMM --------------------
// m in [0,4): Y[n][m][:] = x[n][:] @ basis[m]  (bf16, layout [N][4][128])
// m == 4   : xout[n][:]  = x[n][:] @ root      (fp32)
__global__ __launch_bounds__(256) void gemm5_kernel(
    const float* __restrict__ x, const float* __restrict__ basis,
    const float* __restrict__ root, u16* __restrict__ Y,
    float* __restrict__ xout, int n)
{
    __shared__ float Xs[TILE_N][D];   // 32 KB
    __shared__ float Ws[64][D];       // 32 KB

    const int m = blockIdx.y;
    const float* __restrict__ W = (m < 4) ? (basis + (size_t)m * D * D) : root;
    const int n0 = blockIdx.x * TILE_N;
    const int tid = threadIdx.x;

    {
        const float4* Xv = ((const float4*)x) + (size_t)n0 * 32;
        float4* Xsv = (float4*)&Xs[0][0];
#pragma unroll
        for (int i = 0; i < 8; ++i) {
            int idx = tid + 256 * i;
            int row = idx >> 5;
            float4 v = make_float4(0.f, 0.f, 0.f, 0.f);
            if (n0 + row < n) v = Xv[idx];
            Xsv[idx] = v;
        }
    }

    const int jt = tid & 31;
    const int nt = tid >> 5;

    float4 acc[8];
#pragma unroll
    for (int mm = 0; mm < 8; ++mm) acc[mm] = make_float4(0.f, 0.f, 0.f, 0.f);

    for (int kc = 0; kc < D; kc += 64) {
        __syncthreads();
        {
            const float4* Wv = (const float4*)(W + (size_t)kc * D);
            float4* Wsv = (float4*)&Ws[0][0];
#pragma unroll
            for (int i = 0; i < 8; ++i) Wsv[tid + 256 * i] = Wv[tid + 256 * i];
        }
        __syncthreads();

#pragma unroll 4
        for (int k = 0; k < 64; k += 4) {
            float4 w0 = *(const float4*)&Ws[k + 0][jt * 4];
            float4 w1 = *(const float4*)&Ws[k + 1][jt * 4];
            float4 w2 = *(const float4*)&Ws[k + 2][jt * 4];
            float4 w3 = *(const float4*)&Ws[k + 3][jt * 4];
#pragma unroll
            for (int mm = 0; mm < 8; ++mm) {
                float4 xv = *(const float4*)&Xs[nt * 8 + mm][kc + k];
                acc[mm].x += xv.x * w0.x + xv.y * w1.x + xv.z * w2.x + xv.w * w3.x;
                acc[mm].y += xv.x * w0.y + xv.y * w1.y + xv.z * w2.y + xv.w * w3.y;
                acc[mm].z += xv.x * w0.z + xv.y * w1.z + xv.z * w2.z + xv.w * w3.z;
                acc[mm].w += xv.x * w0.w + xv.y * w1.w + xv.z * w2.w + xv.w * w3.w;
            }
        }
    }

#pragma unroll
    for (int mm = 0; mm < 8; ++mm) {
        int row = n0 + nt * 8 + mm;
        if (row < n) {
            if (m < 4) {
                ushort4 o;
                o.x = f2bf(acc[mm].x); o.y = f2bf(acc[mm].y);
                o.z = f2bf(acc[mm].z); o.w = f2bf(acc[mm].w);
                ((ushort4*)Y)[(size_t)row * 128 + m * 32 + jt] = o;
            } else {
                ((float4*)xout)[(size_t)row * 32 + jt] = acc[mm];
            }
        }
    }
}

// -------------------- primary: edge scatter (bf16 Y) --------------------
__global__ __launch_bounds__(256) void edge_kernel(
    const int* __restrict__ src, const int* __restrict__ dst,
    const int* __restrict__ etype, const float* __restrict__ norm,
    const float* __restrict__ att, const u16* __restrict__ Y,
    float* __restrict__ agg, int E)
{
    int idx = blockIdx.x * 256 + threadIdx.x;
    int e = idx >> 5;
    if (e >= E) return;
    int q = idx & 31;
    int s = src[e], d0 = dst[e], t = etype[e];
    float nm = norm[e];
    float4 c = ((const float4*)att)[t];
    const ushort4* y = ((const ushort4*)Y) + (size_t)s * 128;  // [4][32] ushort4
    ushort4 u0 = y[q], u1 = y[32 + q], u2 = y[64 + q], u3 = y[96 + q];
    float4 mv;
    mv.x = nm * (c.x * bf2f(u0.x) + c.y * bf2f(u1.x) + c.z * bf2f(u2.x) + c.w * bf2f(u3.x));
    mv.y = nm * (c.x * bf2f(u0.y) + c.y * bf2f(u1.y) + c.z * bf2f(u2.y) + c.w * bf2f(u3.y));
    mv.z = nm * (c.x * bf2f(u0.z) + c.y * bf2f(u1.z) + c.z * bf2f(u2.z) + c.w * bf2f(u3.z));
    mv.w = nm * (c.x * bf2f(u0.w) + c.y * bf2f(u1.w) + c.z * bf2f(u2.w) + c.w * bf2f(u3.w));
    float* o = agg + (size_t)d0 * 128 + q * 4;
    atomicAdd(o + 0, mv.x);
    atomicAdd(o + 1, mv.y);
    atomicAdd(o + 2, mv.z);
    atomicAdd(o + 3, mv.w);
}

// -------------------- primary: combine --------------------
__global__ __launch_bounds__(256) void combine_kernel(
    float* __restrict__ xout, const float* __restrict__ agg,
    const float* __restrict__ inv, const float* __restrict__ bias,
    int n, int relu)
{
    int idx = blockIdx.x * 256 + threadIdx.x;
    if (idx >= n * 32) return;
    int row = idx >> 5, j = idx & 31;
    float iv = inv[row];
    float4 a = ((const float4*)agg)[idx];
    float4 b = ((const float4*)bias)[j];
    float4 v = ((float4*)xout)[idx];
    v.x += a.x * iv + b.x;
    v.y += a.y * iv + b.y;
    v.z += a.z * iv + b.z;
    v.w += a.w * iv + b.w;
    if (relu) {
        v.x = fmaxf(v.x, 0.f); v.y = fmaxf(v.y, 0.f);
        v.z = fmaxf(v.z, 0.f); v.w = fmaxf(v.w, 0.f);
    }
    ((float4*)xout)[idx] = v;
}

// -------------------- fallback: single-matrix GEMM -> bf16 --------------------
__global__ __launch_bounds__(256) void gemm1_kernel(
    const float* __restrict__ x, const float* __restrict__ W,
    u16* __restrict__ yout, int n)
{
    __shared__ float Xs[TILE_N][D];
    __shared__ float Ws[64][D];
    const int n0 = blockIdx.x * TILE_N;
    const int tid = threadIdx.x;
    {
        const float4* Xv = ((const float4*)x) + (size_t)n0 * 32;
        float4* Xsv = (float4*)&Xs[0][0];
#pragma unroll
        for (int i = 0; i < 8; ++i) {
            int idx = tid + 256 * i;
            int row = idx >> 5;
            float4 v = make_float4(0.f, 0.f, 0.f, 0.f);
            if (n0 + row < n) v = Xv[idx];
            Xsv[idx] = v;
        }
    }
    const int jt = tid & 31, nt = tid >> 5;
    float4 acc[8];
#pragma unroll
    for (int mm = 0; mm < 8; ++mm) acc[mm] = make_float4(0.f, 0.f, 0.f, 0.f);
    for (int kc = 0; kc < D; kc += 64) {
        __syncthreads();
        {
            const float4* Wv = (const float4*)(W + (size_t)kc * D);
            float4* Wsv = (float4*)&Ws[0][0];
#pragma unroll
            for (int i = 0; i < 8; ++i) Wsv[tid + 256 * i] = Wv[tid + 256 * i];
        }
        __syncthreads();
#pragma unroll 4
        for (int k = 0; k < 64; k += 4) {
            float4 w0 = *(const float4*)&Ws[k + 0][jt * 4];
            float4 w1 = *(const float4*)&Ws[k + 1][jt * 4];
            float4 w2 = *(const float4*)&Ws[k + 2][jt * 4];
            float4 w3 = *(const float4*)&Ws[k + 3][jt * 4];
#pragma unroll
            for (int mm = 0; mm < 8; ++mm) {
                float4 xv = *(const float4*)&Xs[nt * 8 + mm][kc + k];
                acc[mm].x += xv.x * w0.x + xv.y * w1.x + xv.z * w2.x + xv.w * w3.x;
                acc[mm].y += xv.x * w0.y + xv.y * w1.y + xv.z * w2.y + xv.w * w3.y;
                acc[mm].z += xv.x * w0.z + xv.y * w1.z + xv.z * w2.z + xv.w * w3.z;
                acc[mm].w += xv.x * w0.w + xv.y * w1.w + xv.z * w2.w + xv.w * w3.w;
            }
        }
    }
#pragma unroll
    for (int mm = 0; mm < 8; ++mm) {
        int row = n0 + nt * 8 + mm;
        if (row < n) {
            ushort4 o;
            o.x = f2bf(acc[mm].x); o.y = f2bf(acc[mm].y);
            o.z = f2bf(acc[mm].z); o.w = f2bf(acc[mm].w);
            ((ushort4*)yout)[(size_t)row * 32 + jt] = o;
        }
    }
}

// -------------------- fallback: per-basis edge scatter --------------------
__global__ __launch_bounds__(256) void edgeb_kernel(
    const int* __restrict__ src, const int* __restrict__ dst,
    const int* __restrict__ etype, const float* __restrict__ norm,
    const float* __restrict__ att, int b, const u16* __restrict__ tmp,
    float* __restrict__ agg, int E)
{
    int idx = blockIdx.x * 256 + threadIdx.x;
    int e = idx >> 5;
    if (e >= E) return;
    int q = idx & 31;
    int s = src[e], d0 = dst[e], t = etype[e];
    float coef = att[t * NB + b] * norm[e];
    ushort4 u = ((const ushort4*)tmp)[(size_t)s * 32 + q];
    float* o = agg + (size_t)d0 * 128 + q * 4;
    atomicAdd(o + 0, coef * bf2f(u.x));
    atomicAdd(o + 1, coef * bf2f(u.y));
    atomicAdd(o + 2, coef * bf2f(u.z));
    atomicAdd(o + 3, coef * bf2f(u.w));
}

// -------------------- fallback: root GEMM + combine (in-place on io) ------
__global__ __launch_bounds__(256) void rootcomb_kernel(
    const float* __restrict__ x, const float* __restrict__ W,
    float* __restrict__ io, const float* __restrict__ inv,
    const float* __restrict__ bias, int relu, int n)
{
    __shared__ float Xs[TILE_N][D];
    __shared__ float Ws[64][D];
    const int n0 = blockIdx.x * TILE_N;
    const int tid = threadIdx.x;
    {
        const float4* Xv = ((const float4*)x) + (size_t)n0 * 32;
        float4* Xsv = (float4*)&Xs[0][0];
#pragma unroll
        for (int i = 0; i < 8; ++i) {
            int idx = tid + 256 * i;
            int row = idx >> 5;
            float4 v = make_float4(0.f, 0.f, 0.f, 0.f);
            if (n0 + row < n) v = Xv[idx];
            Xsv[idx] = v;
        }
    }
    const int jt = tid & 31, nt = tid >> 5;
    float4 acc[8];
#pragma unroll
    for (int mm = 0; mm < 8; ++mm) acc[mm] = make_float4(0.f, 0.f, 0.f, 0.f);
    for (int kc = 0; kc < D; kc += 64) {
        __syncthreads();
        {
            const float4* Wv = (const float4*)(W + (size_t)kc * D);
            float4* Wsv = (float4*)&Ws[0][0];
#pragma unroll
            for (int i = 0; i < 8; ++i) Wsv[tid + 256 * i] = Wv[tid + 256 * i];
        }
        __syncthreads();
#pragma unroll 4
        for (int k = 0; k < 64; k += 4) {
            float4 w0 = *(const float4*)&Ws[k + 0][jt * 4];
            float4 w1 = *(const float4*)&Ws[k + 1][jt * 4];
            float4 w2 = *(const float4*)&Ws[k + 2][jt * 4];
            float4 w3 = *(const float4*)&Ws[k + 3][jt * 4];
#pragma unroll
            for (int mm = 0; mm < 8; ++mm) {
                float4 xv = *(const float4*)&Xs[nt * 8 + mm][kc + k];
                acc[mm].x += xv.x * w0.x + xv.y * w1.x + xv.z * w2.x + xv.w * w3.x;
                acc[mm].y += xv.x * w0.y + xv.y * w1.y + xv.z * w2.y + xv.w * w3.y;
                acc[mm].z += xv.x * w0.z + xv.y * w1.z + xv.z * w2.z + xv.w * w3.z;
                acc[mm].w += xv.x * w0.w + xv.y * w1.w + xv.z * w2.w + xv.w * w3.w;
            }
        }
    }
    const float4* bi = (const float4*)bias;
#pragma unroll
    for (int mm = 0; mm < 8; ++mm) {
        int row = n0 + nt * 8 + mm;
        if (row < n) {
            float iv = inv[row];
            float4 a = ((float4*)io)[(size_t)row * 32 + jt];
            float4 b4 = bi[jt];
            float4 v;
            v.x = acc[mm].x + a.x * iv + b4.x;
            v.y = acc[mm].y + a.y * iv + b4.y;
            v.z = acc[mm].z + a.z * iv + b4.z;
            v.w = acc[mm].w + a.w * iv + b4.w;
            if (relu) {
                v.x = fmaxf(v.x, 0.f); v.y = fmaxf(v.y, 0.f);
                v.z = fmaxf(v.z, 0.f); v.w = fmaxf(v.w, 0.f);
            }
            ((float4*)io)[(size_t)row * 32 + jt] = v;
        }
    }
}

// -------------------- launch --------------------

extern "C" void kernel_launch(void* const* d_in, const int* in_sizes, int n_in,
                              void* d_out, int out_size, void* d_ws, size_t ws_size,
                              hipStream_t stream) {
    const int*   entity     = (const int*)d_in[0];
    const int*   edge_index = (const int*)d_in[1];
    const int*   edge_type  = (const int*)d_in[2];
    const float* edge_norm  = (const float*)d_in[3];
    const float* emb        = (const float*)d_in[4];
    const float* basis1     = (const float*)d_in[5];
    const float* att1       = (const float*)d_in[6];
    const float* root1      = (const float*)d_in[7];
    const float* bias1      = (const float*)d_in[8];
    const float* basis2     = (const float*)d_in[9];
    const float* att2       = (const float*)d_in[10];
    const float* root2      = (const float*)d_in[11];
    const float* bias2      = (const float*)d_in[12];
    float* out = (float*)d_out;

    const int N = in_sizes[0];
    const int E = in_sizes[2];
    const int* src = edge_index;
    const int* dst = edge_index + E;

    size_t ND = (size_t)N * D;
    char* wp = (char*)d_ws;

    size_t need_primary = ND * 12 + (size_t)N * 4;  // Ybf16(8*ND B) + A(4*ND B) + inv
    size_t need_fb      = ND * 6  + (size_t)N * 4;  // A(4*ND B) + tmp bf16(2*ND B) + inv

    int eblocks = (int)(((long long)E * 32 + 255) / 256);
    int cblocks = (N * 32 + 255) / 256;
    int nblocks = (N + TILE_N - 1) / TILE_N;

    if (ws_size >= need_primary) {
        u16*   Ybf = (u16*)wp;
        float* A   = (float*)(wp + ND * 8);
        float* inv = (float*)(wp + ND * 12);

        hipMemsetAsync(inv, 0, (size_t)N * sizeof(float), stream);
        degree_kernel<<<(E + 255) / 256, 256, 0, stream>>>(dst, inv, E);
        inv_kernel<<<(N + 255) / 256, 256, 0, stream>>>(inv, N);
        gather_kernel<<<cblocks, 256, 0, stream>>>(entity, emb, A, N);

        dim3 g5(nblocks, 5);
        // L1: Xin=A, Xout=out, agg=A(dead after gemm)
        gemm5_kernel<<<g5, 256, 0, stream>>>(A, basis1, root1, Ybf, out, N);
        hipMemsetAsync(A, 0, ND * 4, stream);
        edge_kernel<<<eblocks, 256, 0, stream>>>(src, dst, edge_type, edge_norm, att1, Ybf, A, E);
        combine_kernel<<<cblocks, 256, 0, stream>>>(out, A, inv, bias1, N, 0);
        // L2: Xin=out, Xout=A, agg=out
        gemm5_kernel<<<g5, 256, 0, stream>>>(out, basis1, root1, Ybf, A, N);
        hipMemsetAsync(out, 0, ND * 4, stream);
        edge_kernel<<<eblocks, 256, 0, stream>>>(src, dst, edge_type, edge_norm, att1, Ybf, out, E);
        combine_kernel<<<cblocks, 256, 0, stream>>>(A, out, inv, bias1, N, 1);
        // L3: Xin=A, Xout=out, agg=A
        gemm5_kernel<<<g5, 256, 0, stream>>>(A, basis2, root2, Ybf, out, N);
        hipMemsetAsync(A, 0, ND * 4, stream);
        edge_kernel<<<eblocks, 256, 0, stream>>>(src, dst, edge_type, edge_norm, att2, Ybf, A, E);
        combine_kernel<<<cblocks, 256, 0, stream>>>(out, A, inv, bias2, N, 0);
    } else if (ws_size >= need_fb) {
        float* A   = (float*)wp;
        u16*   tmp = (u16*)(wp + ND * 4);
        float* inv = (float*)(wp + ND * 6);

        hipMemsetAsync(inv, 0, (size_t)N * sizeof(float), stream);
        degree_kernel<<<(E + 255) / 256, 256, 0, stream>>>(dst, inv, E);
        inv_kernel<<<(N + 255) / 256, 256, 0, stream>>>(inv, N);
        gather_kernel<<<cblocks, 256, 0, stream>>>(entity, emb, A, N);

        // L1: Xin=A, Xout=out
        hipMemsetAsync(out, 0, ND * 4, stream);
        for (int b = 0; b < NB; ++b) {
            gemm1_kernel<<<nblocks, 256, 0, stream>>>(A, basis1 + (size_t)b * D * D, tmp, N);
            edgeb_kernel<<<eblocks, 256, 0, stream>>>(src, dst, edge_type, edge_norm, att1, b, tmp, out, E);
        }
        rootcomb_kernel<<<nblocks, 256, 0, stream>>>(A, root1, out, inv, bias1, 0, N);
        // L2: Xin=out, Xout=A
        hipMemsetAsync(A, 0, ND * 4, stream);
        for (int b = 0; b < NB; ++b) {
            gemm1_kernel<<<nblocks, 256, 0, stream>>>(out, basis1 + (size_t)b * D * D, tmp, N);
            edgeb_kernel<<<eblocks, 256, 0, stream>>>(src, dst, edge_type, edge_norm, att1, b, tmp, A, E);
        }
        rootcomb_kernel<<<nblocks, 256, 0, stream>>>(out, root1, A, inv, bias1, 1, N);
        // L3: Xin=A, Xout=out
        hipMemsetAsync(out, 0, ND * 4, stream);
        for (int b = 0; b < NB; ++b) {
            gemm1_kernel<<<nblocks, 256, 0, stream>>>(A, basis2 + (size_t)b * D * D, tmp, N);
            edgeb_kernel<<<eblocks, 256, 0, stream>>>(src, dst, edge_type, edge_norm, att2, b, tmp, out, E);
        }
        rootcomb_kernel<<<nblocks, 256, 0, stream>>>(A, root2, out, inv, bias2, 0, N);
    } else {
        // ws too small for any layout: emit recognizable zero output
        hipMemsetAsync(d_out, 0, (size_t)out_size * sizeof(float), stream);
    }
}

// Round 3
// 1332.088 us; speedup vs baseline: 3.7717x; 3.7717x over previous
//
#include <hip/hip_runtime.h>

#define D 128
#define NB 4
#define TILE_N 64

typedef unsigned short u16;

__device__ __forceinline__ float bf2f(u16 u) {
    union { unsigned int i; float f; } v; v.i = ((unsigned int)u) << 16; return v.f;
}
__device__ __forceinline__ u16 f2bf(float f) {
    union { float ff; unsigned int i; } v; v.ff = f;
    unsigned int r = v.i + 0x7fffu + ((v.i >> 16) & 1u);   // RNE
    return (u16)(r >> 16);
}

// -------------------- CSR build --------------------

__global__ __launch_bounds__(256) void degree_int_kernel(const int* __restrict__ dst,
                                                         int* __restrict__ deg, int E) {
    int e = blockIdx.x * 256 + threadIdx.x;
    if (e < E) atomicAdd(&deg[dst[e]], 1);
}

// single-block exclusive scan over deg -> row_start; also inv = 1/max(deg,1)
__global__ __launch_bounds__(1024) void scan_kernel(const int* __restrict__ deg,
                                                    int* __restrict__ row_start,
                                                    float* __restrict__ inv, int n, int E) {
    __shared__ int buf[1024];
    __shared__ int carry;
    if (threadIdx.x == 0) carry = 0;
    __syncthreads();
    for (int base = 0; base < n; base += 1024) {
        int i = base + threadIdx.x;
        int v = (i < n) ? deg[i] : 0;
        buf[threadIdx.x] = v;
        __syncthreads();
        for (int off = 1; off < 1024; off <<= 1) {
            int t = (threadIdx.x >= (unsigned)off) ? buf[threadIdx.x - off] : 0;
            __syncthreads();
            buf[threadIdx.x] += t;
            __syncthreads();
        }
        if (i < n) {
            row_start[i] = carry + buf[threadIdx.x] - v;   // exclusive
            inv[i] = 1.0f / fmaxf((float)v, 1.0f);
        }
        __syncthreads();
        if (threadIdx.x == 0) carry += buf[1023];
        __syncthreads();
    }
    if (threadIdx.x == 0) row_start[n] = E;
}

__global__ __launch_bounds__(256) void fill_kernel(
    const int* __restrict__ src, const int* __restrict__ dst,
    const int* __restrict__ etype, const float* __restrict__ norm,
    const float* __restrict__ att, const int* __restrict__ row_start,
    int* __restrict__ fill, int* __restrict__ csr_src,
    float4* __restrict__ csr_coef, int E)
{
    int e = blockIdx.x * 256 + threadIdx.x;
    if (e >= E) return;
    int d0 = dst[e];
    int pos = row_start[d0] + atomicAdd(&fill[d0], 1);
    csr_src[pos] = src[e];
    float nm = norm[e];
    float4 a = ((const float4*)att)[etype[e]];
    csr_coef[pos] = make_float4(a.x * nm, a.y * nm, a.z * nm, a.w * nm);
}

// -------------------- gather emb -> bf16 x0 --------------------

__global__ __launch_bounds__(256) void tobf_gather_kernel(const int* __restrict__ entity,
                                                          const float* __restrict__ emb,
                                                          u16* __restrict__ xbf, int n) {
    int idx = blockIdx.x * 256 + threadIdx.x;   // ushort4 index over n*32
    if (idx >= n * 32) return;
    int row = idx >> 5, c = idx & 31;
    float4 v = ((const float4*)emb)[(size_t)entity[row] * 32 + c];
    ushort4 o;
    o.x = f2bf(v.x); o.y = f2bf(v.y); o.z = f2bf(v.z); o.w = f2bf(v.w);
    ((ushort4*)xbf)[idx] = o;
}

// -------------------- CSR aggregation: Z[dst][b][:] = inv * sum_e c_b * x[src] ----
// 32 lanes per node, 8 nodes per 256-thread block.
__global__ __launch_bounds__(256) void agg_kernel(
    const int* __restrict__ row_start, const int* __restrict__ deg,
    const float* __restrict__ inv, const int* __restrict__ csr_src,
    const float4* __restrict__ csr_coef, const u16* __restrict__ xbf,
    u16* __restrict__ Zbf, int n)
{
    int nd = blockIdx.x * 8 + (threadIdx.x >> 5);
    if (nd >= n) return;
    int q = threadIdx.x & 31;
    int s0 = row_start[nd];
    int dg = deg[nd];
    float4 z0 = make_float4(0.f,0.f,0.f,0.f), z1 = z0, z2 = z0, z3 = z0;
    for (int i = 0; i < dg; ++i) {
        int s = csr_src[s0 + i];
        float4 c = csr_coef[s0 + i];
        ushort4 u = ((const ushort4*)xbf)[(size_t)s * 32 + q];
        float4 xv;
        xv.x = bf2f(u.x); xv.y = bf2f(u.y); xv.z = bf2f(u.z); xv.w = bf2f(u.w);
        z0.x += c.x * xv.x; z0.y += c.x * xv.y; z0.z += c.x * xv.z; z0.w += c.x * xv.w;
        z1.x += c.y * xv.x; z1.y += c.y * xv.y; z1.z += c.y * xv.z; z1.w += c.y * xv.w;
        z2.x += c.z * xv.x; z2.y += c.z * xv.y; z2.z += c.z * xv.z; z2.w += c.z * xv.w;
        z3.x += c.w * xv.x; z3.y += c.w * xv.y; z3.z += c.w * xv.z; z3.w += c.w * xv.w;
    }
    float iv = inv[nd];
    ushort4* zp = ((ushort4*)Zbf) + (size_t)nd * 128;   // [4][32] ushort4
    ushort4 o;
    o.x = f2bf(z0.x * iv); o.y = f2bf(z0.y * iv); o.z = f2bf(z0.z * iv); o.w = f2bf(z0.w * iv);
    zp[q] = o;
    o.x = f2bf(z1.x * iv); o.y = f2bf(z1.y * iv); o.z = f2bf(z1.z * iv); o.w = f2bf(z1.w * iv);
    zp[32 + q] = o;
    o.x = f2bf(z2.x * iv); o.y = f2bf(z2.y * iv); o.z = f2bf(z2.z * iv); o.w = f2bf(z2.w * iv);
    zp[64 + q] = o;
    o.x = f2bf(z3.x * iv); o.y = f2bf(z3.y * iv); o.z = f2bf(z3.z * iv); o.w = f2bf(z3.w * iv);
    zp[96 + q] = o;
}

// -------------------- fused layer GEMM --------------------
// out[n][j] = sum_{K=512} Zbf[n][K]*basisW[K][j] + sum_{k=128} xbf[n][k]*root[k][j]
//             + bias[j]  (optional relu); writes bf16 (obf) or fp32 (of32)
__global__ __launch_bounds__(256) void gemmZ_kernel(
    const u16* __restrict__ Zbf, const u16* __restrict__ xbf,
    const float* __restrict__ basisW, const float* __restrict__ root,
    const float* __restrict__ bias, int relu, int write_bf,
    u16* __restrict__ obf, float* __restrict__ of32, int n)
{
    __shared__ float Ws[64][D];    // 32 KB
    __shared__ float Zs[64][64];   // 16 KB

    const int n0 = blockIdx.x * TILE_N;
    const int tid = threadIdx.x;
    const int jt = tid & 31;
    const int nt = tid >> 5;

    float4 acc[8];
#pragma unroll
    for (int mm = 0; mm < 8; ++mm) acc[mm] = make_float4(0.f,0.f,0.f,0.f);

    for (int c = 0; c < 10; ++c) {
        const float* W = (c < 8) ? (basisW + (size_t)c * 64 * D)
                                 : (root + (size_t)(c - 8) * 64 * D);
        const u16* Zp;
        int zstride;
        if (c < 8) { Zp = Zbf + (size_t)n0 * 512 + c * 64;       zstride = 512; }
        else       { Zp = xbf + (size_t)n0 * 128 + (c - 8) * 64; zstride = 128; }

        __syncthreads();
        {   // stage W rows: 2048 float4
            const float4* Wv = (const float4*)W;
            float4* Wsv = (float4*)&Ws[0][0];
#pragma unroll
            for (int i = 0; i < 8; ++i) Wsv[tid + 256 * i] = Wv[tid + 256 * i];
        }
        {   // stage Z tile (bf16 -> f32): 1024 ushort4
#pragma unroll
            for (int i = 0; i < 4; ++i) {
                int idx = tid + 256 * i;
                int r = idx >> 4, c4 = idx & 15;
                float4 v = make_float4(0.f,0.f,0.f,0.f);
                if (n0 + r < n) {
                    ushort4 u = *(const ushort4*)(Zp + (size_t)r * zstride + c4 * 4);
                    v.x = bf2f(u.x); v.y = bf2f(u.y); v.z = bf2f(u.z); v.w = bf2f(u.w);
                }
                *(float4*)&Zs[r][c4 * 4] = v;
            }
        }
        __syncthreads();

#pragma unroll 4
        for (int k = 0; k < 64; k += 4) {
            float4 w0 = *(const float4*)&Ws[k + 0][jt * 4];
            float4 w1 = *(const float4*)&Ws[k + 1][jt * 4];
            float4 w2 = *(const float4*)&Ws[k + 2][jt * 4];
            float4 w3 = *(const float4*)&Ws[k + 3][jt * 4];
#pragma unroll
            for (int mm = 0; mm < 8; ++mm) {
                float4 zv = *(const float4*)&Zs[nt * 8 + mm][k];
                acc[mm].x += zv.x * w0.x + zv.y * w1.x + zv.z * w2.x + zv.w * w3.x;
                acc[mm].y += zv.x * w0.y + zv.y * w1.y + zv.z * w2.y + zv.w * w3.y;
                acc[mm].z += zv.x * w0.z + zv.y * w1.z + zv.z * w2.z + zv.w * w3.z;
                acc[mm].w += zv.x * w0.w + zv.y * w1.w + zv.z * w2.w + zv.w * w3.w;
            }
        }
    }

    const float4* bi = (const float4*)bias;
    float4 b4 = bi[jt];
#pragma unroll
    for (int mm = 0; mm < 8; ++mm) {
        int row = n0 + nt * 8 + mm;
        if (row < n) {
            float4 v = acc[mm];
            v.x += b4.x; v.y += b4.y; v.z += b4.z; v.w += b4.w;
            if (relu) {
                v.x = fmaxf(v.x, 0.f); v.y = fmaxf(v.y, 0.f);
                v.z = fmaxf(v.z, 0.f); v.w = fmaxf(v.w, 0.f);
            }
            if (write_bf) {
                ushort4 o;
                o.x = f2bf(v.x); o.y = f2bf(v.y); o.z = f2bf(v.z); o.w = f2bf(v.w);
                ((ushort4*)obf)[(size_t)row * 32 + jt] = o;
            } else {
                ((float4*)of32)[(size_t)row * 32 + jt] = v;
            }
        }
    }
}

// -------------------- launch --------------------

extern "C" void kernel_launch(void* const* d_in, const int* in_sizes, int n_in,
                              void* d_out, int out_size, void* d_ws, size_t ws_size,
                              hipStream_t stream) {
    const int*   entity     = (const int*)d_in[0];
    const int*   edge_index = (const int*)d_in[1];
    const int*   edge_type  = (const int*)d_in[2];
    const float* edge_norm  = (const float*)d_in[3];
    const float* emb        = (const float*)d_in[4];
    const float* basis1     = (const float*)d_in[5];
    const float* att1       = (const float*)d_in[6];
    const float* root1      = (const float*)d_in[7];
    const float* bias1      = (const float*)d_in[8];
    const float* basis2     = (const float*)d_in[9];
    const float* att2       = (const float*)d_in[10];
    const float* root2      = (const float*)d_in[11];
    const float* bias2      = (const float*)d_in[12];
    float* out = (float*)d_out;

    const int N = in_sizes[0];
    const int E = in_sizes[2];
    const int* src = edge_index;
    const int* dst = edge_index + E;

    size_t ND = (size_t)N * D;
    char* wp = (char*)d_ws;

    // layout (all offsets 16B-aligned):
    size_t off = 0;
    u16*    Zbf      = (u16*)(wp + off);  off += ND * 8;          // N*512 bf16
    u16*    xbf0     = (u16*)(wp + off);  off += ND * 2;          // N*128 bf16
    float4* csr_coef = (float4*)(wp + off); off += (size_t)E * 16;
    int*    csr_src  = (int*)(wp + off);  off += (size_t)E * 4;
    int*    deg      = (int*)(wp + off);  off += (size_t)N * 4;
    int*    fill     = (int*)(wp + off);  off += (size_t)N * 4;
    float*  inv      = (float*)(wp + off); off += (size_t)N * 4;
    int*    row_start= (int*)(wp + off);  off += (size_t)(N + 1) * 4;
    size_t need = off;

    if (ws_size < need) {
        hipMemsetAsync(d_out, 0, (size_t)out_size * sizeof(float), stream);
        return;
    }

    u16* xbf1 = (u16*)d_out;   // scratch inside d_out; fully rewritten by final GEMM

    int eblk = (E + 255) / 256;
    int nblk = (N + TILE_N - 1) / TILE_N;
    int ablk = (N + 7) / 8;
    int gblk = (N * 32 + 255) / 256;

    // ---- CSR build (once; degrees layer-invariant) ----
    hipMemsetAsync(deg, 0, (size_t)N * 4, stream);
    degree_int_kernel<<<eblk, 256, 0, stream>>>(dst, deg, E);
    scan_kernel<<<1, 1024, 0, stream>>>(deg, row_start, inv, N, E);
    hipMemsetAsync(fill, 0, (size_t)N * 4, stream);
    fill_kernel<<<eblk, 256, 0, stream>>>(src, dst, edge_type, edge_norm, att1 /*unused below per layer? no: coef uses att1*/, row_start, fill, csr_src, csr_coef, E);
    tobf_gather_kernel<<<gblk, 256, 0, stream>>>(entity, emb, xbf0, N);

    // NOTE: csr_coef above baked att1; layers 1&2 use att1. Layer 3 needs att2:
    // rebuild coef only (src order identical? not guaranteed across fills — so
    // rebuild the whole fill for layer 3 to keep src/coef consistent).

    // ---- layer 1: in xbf0 -> out xbf1 ----
    agg_kernel<<<ablk, 256, 0, stream>>>(row_start, deg, inv, csr_src, csr_coef, xbf0, Zbf, N);
    gemmZ_kernel<<<nblk, 256, 0, stream>>>(Zbf, xbf0, basis1, root1, bias1, 0, 1, xbf1, nullptr, N);

    // ---- layer 2: in xbf1 -> out xbf0 (relu) ----
    agg_kernel<<<ablk, 256, 0, stream>>>(row_start, deg, inv, csr_src, csr_coef, xbf1, Zbf, N);
    gemmZ_kernel<<<nblk, 256, 0, stream>>>(Zbf, xbf1, basis1, root1, bias1, 1, 1, xbf0, nullptr, N);

    // ---- layer 3: rebuild coef with att2, in xbf0 -> out fp32 ----
    hipMemsetAsync(fill, 0, (size_t)N * 4, stream);
    fill_kernel<<<eblk, 256, 0, stream>>>(src, dst, edge_type, edge_norm, att2, row_start, fill, csr_src, csr_coef, E);
    agg_kernel<<<ablk, 256, 0, stream>>>(row_start, deg, inv, csr_src, csr_coef, xbf0, Zbf, N);
    gemmZ_kernel<<<nblk, 256, 0, stream>>>(Zbf, xbf0, basis2, root2, bias2, 0, 0, nullptr, out, N);
}

// Round 4
// 807.876 us; speedup vs baseline: 6.2191x; 1.6489x over previous
//
#include <hip/hip_runtime.h>

#define D 128
#define NB 4
#define TILE_N 64
#define BM 128
#define LDK 72   // padded LDS row length in bf16 (64 + 8)

typedef unsigned short u16;
typedef unsigned int u32;
using bf16x8 = __attribute__((ext_vector_type(8))) short;
using f32x4  = __attribute__((ext_vector_type(4))) float;

__device__ __forceinline__ float bf2f(u16 u) {
    union { u32 i; float f; } v; v.i = ((u32)u) << 16; return v.f;
}
__device__ __forceinline__ u16 f2bf(float f) {
    union { float ff; u32 i; } v; v.ff = f;
    u32 r = v.i + 0x7fffu + ((v.i >> 16) & 1u);   // RNE
    return (u16)(r >> 16);
}

// -------------------- CSR build --------------------

__global__ __launch_bounds__(256) void degree_int_kernel(const int* __restrict__ dst,
                                                         int* __restrict__ deg, int E) {
    int e = blockIdx.x * 256 + threadIdx.x;
    if (e < E) atomicAdd(&deg[dst[e]], 1);
}

__global__ __launch_bounds__(1024) void scan_kernel(const int* __restrict__ deg,
                                                    int* __restrict__ row_start,
                                                    float* __restrict__ inv, int n, int E) {
    __shared__ int buf[1024];
    __shared__ int carry;
    if (threadIdx.x == 0) carry = 0;
    __syncthreads();
    for (int base = 0; base < n; base += 1024) {
        int i = base + threadIdx.x;
        int v = (i < n) ? deg[i] : 0;
        buf[threadIdx.x] = v;
        __syncthreads();
        for (int off = 1; off < 1024; off <<= 1) {
            int t = (threadIdx.x >= (unsigned)off) ? buf[threadIdx.x - off] : 0;
            __syncthreads();
            buf[threadIdx.x] += t;
            __syncthreads();
        }
        if (i < n) {
            row_start[i] = carry + buf[threadIdx.x] - v;   // exclusive
            inv[i] = 1.0f / fmaxf((float)v, 1.0f);
        }
        __syncthreads();
        if (threadIdx.x == 0) carry += buf[1023];
        __syncthreads();
    }
    if (threadIdx.x == 0) row_start[n] = E;
}

__global__ __launch_bounds__(256) void fill_kernel(
    const int* __restrict__ src, const int* __restrict__ dst,
    const int* __restrict__ etype, const float* __restrict__ norm,
    const float* __restrict__ att, const int* __restrict__ row_start,
    int* __restrict__ fill, int* __restrict__ csr_src,
    float4* __restrict__ csr_coef, int E)
{
    int e = blockIdx.x * 256 + threadIdx.x;
    if (e >= E) return;
    int d0 = dst[e];
    int pos = row_start[d0] + atomicAdd(&fill[d0], 1);
    csr_src[pos] = src[e];
    float nm = norm[e];
    float4 a = ((const float4*)att)[etype[e]];
    csr_coef[pos] = make_float4(a.x * nm, a.y * nm, a.z * nm, a.w * nm);
}

// -------------------- gather emb -> bf16 x0 --------------------

__global__ __launch_bounds__(256) void tobf_gather_kernel(const int* __restrict__ entity,
                                                          const float* __restrict__ emb,
                                                          u16* __restrict__ xbf, int n) {
    int idx = blockIdx.x * 256 + threadIdx.x;   // ushort4 index over n*32
    if (idx >= n * 32) return;
    int row = idx >> 5, c = idx & 31;
    float4 v = ((const float4*)emb)[(size_t)entity[row] * 32 + c];
    ushort4 o;
    o.x = f2bf(v.x); o.y = f2bf(v.y); o.z = f2bf(v.z); o.w = f2bf(v.w);
    ((ushort4*)xbf)[idx] = o;
}

// -------------------- CSR aggregation --------------------
__global__ __launch_bounds__(256) void agg_kernel(
    const int* __restrict__ row_start, const int* __restrict__ deg,
    const float* __restrict__ inv, const int* __restrict__ csr_src,
    const float4* __restrict__ csr_coef, const u16* __restrict__ xbf,
    u16* __restrict__ Zbf, int n)
{
    int nd = blockIdx.x * 8 + (threadIdx.x >> 5);
    if (nd >= n) return;
    int q = threadIdx.x & 31;
    int s0 = row_start[nd];
    int dg = deg[nd];
    float4 z0 = make_float4(0.f,0.f,0.f,0.f), z1 = z0, z2 = z0, z3 = z0;
    for (int i = 0; i < dg; ++i) {
        int s = csr_src[s0 + i];
        float4 c = csr_coef[s0 + i];
        ushort4 u = ((const ushort4*)xbf)[(size_t)s * 32 + q];
        float4 xv;
        xv.x = bf2f(u.x); xv.y = bf2f(u.y); xv.z = bf2f(u.z); xv.w = bf2f(u.w);
        z0.x += c.x * xv.x; z0.y += c.x * xv.y; z0.z += c.x * xv.z; z0.w += c.x * xv.w;
        z1.x += c.y * xv.x; z1.y += c.y * xv.y; z1.z += c.y * xv.z; z1.w += c.y * xv.w;
        z2.x += c.z * xv.x; z2.y += c.z * xv.y; z2.z += c.z * xv.z; z2.w += c.z * xv.w;
        z3.x += c.w * xv.x; z3.y += c.w * xv.y; z3.z += c.w * xv.z; z3.w += c.w * xv.w;
    }
    float iv = inv[nd];
    ushort4* zp = ((ushort4*)Zbf) + (size_t)nd * 128;   // [4][32] ushort4
    ushort4 o;
    o.x = f2bf(z0.x * iv); o.y = f2bf(z0.y * iv); o.z = f2bf(z0.z * iv); o.w = f2bf(z0.w * iv);
    zp[q] = o;
    o.x = f2bf(z1.x * iv); o.y = f2bf(z1.y * iv); o.z = f2bf(z1.z * iv); o.w = f2bf(z1.w * iv);
    zp[32 + q] = o;
    o.x = f2bf(z2.x * iv); o.y = f2bf(z2.y * iv); o.z = f2bf(z2.z * iv); o.w = f2bf(z2.w * iv);
    zp[64 + q] = o;
    o.x = f2bf(z3.x * iv); o.y = f2bf(z3.y * iv); o.z = f2bf(z3.z * iv); o.w = f2bf(z3.w * iv);
    zp[96 + q] = o;
}

// -------------------- weight prep: transpose + hi/lo bf16 split --------------------
// Wt[n][k], n in [0,128), k in [0,1280): k<640 = bf16(W[k][n]),
// k>=640 = bf16(W[k-640][n] - bf16(W[k-640][n])).  W = [basis(512 rows) ; root(128 rows)]
__global__ __launch_bounds__(256) void wprep_kernel(
    const float* __restrict__ basis, const float* __restrict__ root,
    u16* __restrict__ Wt)
{
    int idx = blockIdx.x * 256 + threadIdx.x;  // over 640*128
    if (idx >= 640 * 128) return;
    int k = idx >> 7, nn = idx & 127;
    float w = (k < 512) ? basis[(size_t)k * 128 + nn] : root[(size_t)(k - 512) * 128 + nn];
    u16 hi = f2bf(w);
    float lo = w - bf2f(hi);
    Wt[(size_t)nn * 1280 + k] = hi;
    Wt[(size_t)nn * 1280 + 640 + k] = f2bf(lo);
}

// -------------------- MFMA layer GEMM --------------------
// out[M][128] = [Zbf | xbf](M x 640, bf16) @ W(640 x 128, hi+lo bf16) + bias
__global__ __launch_bounds__(256) void mfma_gemm_kernel(
    const u16* __restrict__ Zbf, const u16* __restrict__ xbf,
    const u16* __restrict__ Wt, const float* __restrict__ bias,
    int relu, int write_bf, u16* __restrict__ obf, float* __restrict__ of32, int n)
{
    __shared__ u16 As[BM][LDK];   // 18 KB
    __shared__ u16 Bs[BM][LDK];   // 18 KB (n-major: Bs[n][k])

    const int tid = threadIdx.x;
    const int row0 = blockIdx.x * BM;
    const int l  = tid & 63;
    const int w  = tid >> 6;
    const int wr = (w >> 1) * 64;   // wave row offset
    const int wc = (w & 1) * 64;    // wave col offset
    const int lr = l & 15;          // fragment M-row (A) / N-col (B)
    const int lk = l >> 4;          // k-group (0..3) -> k offset lk*8

    f32x4 zero = {0.f, 0.f, 0.f, 0.f};
    f32x4 acc[4][4];
#pragma unroll
    for (int mi = 0; mi < 4; ++mi)
#pragma unroll
        for (int ni = 0; ni < 4; ++ni) acc[mi][ni] = zero;

    for (int s = 0; s < 20; ++s) {
        const int ac = s >> 1;                     // A chunk 0..9
        const int wk = (s & 1) * 640 + ac * 64;    // Wt k-offset (hi then lo)
        __syncthreads();
        if ((s & 1) == 0) {
            // stage A chunk: 128 rows x 64 bf16 = 1024 x 16B granules
#pragma unroll
            for (int i = 0; i < 4; ++i) {
                int g = tid + i * 256;
                int r = g >> 3, sl = g & 7;
                int grow = row0 + r;
                uint4 v = make_uint4(0u, 0u, 0u, 0u);
                if (grow < n) {
                    const u16* p = (ac < 8)
                        ? (Zbf + (size_t)grow * 512 + ac * 64 + sl * 8)
                        : (xbf + (size_t)grow * 128 + (ac - 8) * 64 + sl * 8);
                    v = *(const uint4*)p;
                }
                *(uint4*)&As[r][sl * 8] = v;
            }
        }
        // stage B chunk (Wt rows are output-cols)
#pragma unroll
        for (int i = 0; i < 4; ++i) {
            int g = tid + i * 256;
            int r = g >> 3, sl = g & 7;
            uint4 v = *(const uint4*)(Wt + (size_t)r * 1280 + wk + sl * 8);
            *(uint4*)&Bs[r][sl * 8] = v;
        }
        __syncthreads();

#pragma unroll
        for (int kh = 0; kh < 2; ++kh) {
            bf16x8 af[4], bfr[4];
#pragma unroll
            for (int mi = 0; mi < 4; ++mi)
                af[mi] = *(const bf16x8*)&As[wr + mi * 16 + lr][kh * 32 + lk * 8];
#pragma unroll
            for (int ni = 0; ni < 4; ++ni)
                bfr[ni] = *(const bf16x8*)&Bs[wc + ni * 16 + lr][kh * 32 + lk * 8];
#pragma unroll
            for (int mi = 0; mi < 4; ++mi)
#pragma unroll
                for (int ni = 0; ni < 4; ++ni)
                    acc[mi][ni] = __builtin_amdgcn_mfma_f32_16x16x32_bf16(
                        af[mi], bfr[ni], acc[mi][ni], 0, 0, 0);
        }
    }

    // epilogue: C/D layout col = lane&15, row = (lane>>4)*4 + reg
#pragma unroll
    for (int ni = 0; ni < 4; ++ni) {
        int col = wc + ni * 16 + lr;
        float bv = bias[col];
#pragma unroll
        for (int mi = 0; mi < 4; ++mi) {
#pragma unroll
            for (int r = 0; r < 4; ++r) {
                int row = row0 + wr + mi * 16 + lk * 4 + r;
                if (row < n) {
                    float v = acc[mi][ni][r] + bv;
                    if (relu) v = fmaxf(v, 0.f);
                    if (write_bf) obf[(size_t)row * 128 + col] = f2bf(v);
                    else          of32[(size_t)row * 128 + col] = v;
                }
            }
        }
    }
}

// -------------------- launch --------------------

extern "C" void kernel_launch(void* const* d_in, const int* in_sizes, int n_in,
                              void* d_out, int out_size, void* d_ws, size_t ws_size,
                              hipStream_t stream) {
    const int*   entity     = (const int*)d_in[0];
    const int*   edge_index = (const int*)d_in[1];
    const int*   edge_type  = (const int*)d_in[2];
    const float* edge_norm  = (const float*)d_in[3];
    const float* emb        = (const float*)d_in[4];
    const float* basis1     = (const float*)d_in[5];
    const float* att1       = (const float*)d_in[6];
    const float* root1      = (const float*)d_in[7];
    const float* bias1      = (const float*)d_in[8];
    const float* basis2     = (const float*)d_in[9];
    const float* att2       = (const float*)d_in[10];
    const float* root2      = (const float*)d_in[11];
    const float* bias2      = (const float*)d_in[12];
    float* out = (float*)d_out;

    const int N = in_sizes[0];
    const int E = in_sizes[2];
    const int* src = edge_index;
    const int* dst = edge_index + E;

    size_t ND = (size_t)N * D;
    char* wp = (char*)d_ws;

    size_t off = 0;
    u16*    Zbf      = (u16*)(wp + off);   off += ND * 8;            // N*512 bf16
    u16*    xbf0     = (u16*)(wp + off);   off += ND * 2;            // N*128 bf16
    u16*    Wt       = (u16*)(wp + off);   off += (size_t)128 * 1280 * 2;
    float4* csr_coef = (float4*)(wp + off); off += (size_t)E * 16;
    int*    csr_src  = (int*)(wp + off);   off += (size_t)E * 4;
    int*    deg      = (int*)(wp + off);   off += (size_t)N * 4;
    int*    fill     = (int*)(wp + off);   off += (size_t)N * 4;
    float*  inv      = (float*)(wp + off); off += (size_t)N * 4;
    int*    row_start= (int*)(wp + off);   off += (size_t)(N + 1) * 4;
    size_t need = off;

    if (ws_size < need) {
        hipMemsetAsync(d_out, 0, (size_t)out_size * sizeof(float), stream);
        return;
    }

    u16* xbf1 = (u16*)d_out;   // bf16 scratch inside d_out; overwritten by final fp32 GEMM

    int eblk = (E + 255) / 256;
    int ablk = (N + 7) / 8;
    int gblk = (N * 32 + 255) / 256;
    int mblk = (N + BM - 1) / BM;
    int wblk = (640 * 128 + 255) / 256;

    // ---- CSR build (degrees layer-invariant; coef baked per att) ----
    hipMemsetAsync(deg, 0, (size_t)N * 4, stream);
    degree_int_kernel<<<eblk, 256, 0, stream>>>(dst, deg, E);
    scan_kernel<<<1, 1024, 0, stream>>>(deg, row_start, inv, N, E);
    hipMemsetAsync(fill, 0, (size_t)N * 4, stream);
    fill_kernel<<<eblk, 256, 0, stream>>>(src, dst, edge_type, edge_norm, att1,
                                          row_start, fill, csr_src, csr_coef, E);
    tobf_gather_kernel<<<gblk, 256, 0, stream>>>(entity, emb, xbf0, N);
    wprep_kernel<<<wblk, 256, 0, stream>>>(basis1, root1, Wt);

    // ---- layer 1: xbf0 -> xbf1 ----
    agg_kernel<<<ablk, 256, 0, stream>>>(row_start, deg, inv, csr_src, csr_coef, xbf0, Zbf, N);
    mfma_gemm_kernel<<<mblk, 256, 0, stream>>>(Zbf, xbf0, Wt, bias1, 0, 1, xbf1, nullptr, N);

    // ---- layer 2: xbf1 -> xbf0 (relu) ----
    agg_kernel<<<ablk, 256, 0, stream>>>(row_start, deg, inv, csr_src, csr_coef, xbf1, Zbf, N);
    mfma_gemm_kernel<<<mblk, 256, 0, stream>>>(Zbf, xbf1, Wt, bias1, 1, 1, xbf0, nullptr, N);

    // ---- layer 3: rebuild coef with att2, new weights; xbf0 -> out (fp32) ----
    hipMemsetAsync(fill, 0, (size_t)N * 4, stream);
    fill_kernel<<<eblk, 256, 0, stream>>>(src, dst, edge_type, edge_norm, att2,
                                          row_start, fill, csr_src, csr_coef, E);
    wprep_kernel<<<wblk, 256, 0, stream>>>(basis2, root2, Wt);
    agg_kernel<<<ablk, 256, 0, stream>>>(row_start, deg, inv, csr_src, csr_coef, xbf0, Zbf, N);
    mfma_gemm_kernel<<<mblk, 256, 0, stream>>>(Zbf, xbf0, Wt, bias2, 0, 0, nullptr, out, N);
}

// Round 5
// 611.400 us; speedup vs baseline: 8.2176x; 1.3214x over previous
//
#include <hip/hip_runtime.h>

#define D 128
#define NB 4
#define BM 128
#define LDK 72   // padded LDS row length in bf16 (64 + 8)
#define SCAN_B 1024

typedef unsigned short u16;
typedef unsigned int u32;
using bf16x8 = __attribute__((ext_vector_type(8))) short;
using f32x4  = __attribute__((ext_vector_type(4))) float;

__device__ __forceinline__ float bf2f(u16 u) {
    union { u32 i; float f; } v; v.i = ((u32)u) << 16; return v.f;
}
__device__ __forceinline__ u16 f2bf(float f) {
    union { float ff; u32 i; } v; v.ff = f;
    u32 r = v.i + 0x7fffu + ((v.i >> 16) & 1u);   // RNE
    return (u16)(r >> 16);
}

// -------------------- CSR build --------------------

__global__ __launch_bounds__(256) void degree_int_kernel(const int* __restrict__ dst,
                                                         int* __restrict__ deg, int E) {
    int e = blockIdx.x * 256 + threadIdx.x;
    if (e < E) atomicAdd(&deg[dst[e]], 1);
}

// stage 1: per-block (1024 elems) local exclusive scan -> row_start, block sum -> bsum
__global__ __launch_bounds__(256) void scan1_kernel(const int* __restrict__ deg,
                                                    int* __restrict__ row_start,
                                                    int* __restrict__ bsum, int n) {
    __shared__ int tsum[256];
    int base = blockIdx.x * SCAN_B;
    int t = threadIdx.x;
    int v[4];
    int s = 0;
#pragma unroll
    for (int i = 0; i < 4; ++i) {
        int idx = base + t * 4 + i;
        v[i] = (idx < n) ? deg[idx] : 0;
        s += v[i];
    }
    tsum[t] = s;
    __syncthreads();
    for (int off = 1; off < 256; off <<= 1) {
        int x = (t >= off) ? tsum[t - off] : 0;
        __syncthreads();
        tsum[t] += x;
        __syncthreads();
    }
    int run = tsum[t] - s;   // exclusive prefix of this thread within block
#pragma unroll
    for (int i = 0; i < 4; ++i) {
        int idx = base + t * 4 + i;
        if (idx < n) row_start[idx] = run;
        run += v[i];
    }
    if (t == 255) bsum[blockIdx.x] = tsum[255];
}

// stage 2: single small block scans the block sums (exclusive, in place)
__global__ __launch_bounds__(256) void scan2_kernel(int* __restrict__ bsum, int nb) {
    __shared__ int buf[256];
    __shared__ int carry_s;
    if (threadIdx.x == 0) carry_s = 0;
    __syncthreads();
    for (int base = 0; base < nb; base += 256) {
        int i = base + threadIdx.x;
        int v = (i < nb) ? bsum[i] : 0;
        buf[threadIdx.x] = v;
        __syncthreads();
        for (int off = 1; off < 256; off <<= 1) {
            int x = (threadIdx.x >= (unsigned)off) ? buf[threadIdx.x - off] : 0;
            __syncthreads();
            buf[threadIdx.x] += x;
            __syncthreads();
        }
        if (i < nb) bsum[i] = carry_s + buf[threadIdx.x] - v;
        __syncthreads();
        if (threadIdx.x == 0) carry_s += buf[255];
        __syncthreads();
    }
}

// stage 3: add block offsets, compute inv, terminate row_start
__global__ __launch_bounds__(256) void scan3_kernel(const int* __restrict__ deg,
                                                    const int* __restrict__ bsum,
                                                    int* __restrict__ row_start,
                                                    float* __restrict__ inv, int n, int E) {
    int i = blockIdx.x * 256 + threadIdx.x;
    if (i < n) {
        row_start[i] += bsum[i >> 10];
        inv[i] = 1.0f / fmaxf((float)deg[i], 1.0f);
    }
    if (i == 0) row_start[n] = E;
}

// fill: CSR permutation only (src + original edge id); coef generated per layer
__global__ __launch_bounds__(256) void fill_kernel(
    const int* __restrict__ src, const int* __restrict__ dst,
    const int* __restrict__ row_start, int* __restrict__ fill,
    int* __restrict__ csr_src, int* __restrict__ csr_eid, int E)
{
    int e = blockIdx.x * 256 + threadIdx.x;
    if (e >= E) return;
    int d0 = dst[e];
    int pos = row_start[d0] + atomicAdd(&fill[d0], 1);
    csr_src[pos] = src[e];
    csr_eid[pos] = e;
}

__global__ __launch_bounds__(256) void coef_kernel(
    const int* __restrict__ csr_eid, const int* __restrict__ etype,
    const float* __restrict__ norm, const float* __restrict__ att,
    float4* __restrict__ csr_coef, int E)
{
    int p = blockIdx.x * 256 + threadIdx.x;
    if (p >= E) return;
    int e = csr_eid[p];
    float nm = norm[e];
    float4 a = ((const float4*)att)[etype[e]];
    csr_coef[p] = make_float4(a.x * nm, a.y * nm, a.z * nm, a.w * nm);
}

// -------------------- gather emb -> bf16 x0 --------------------

__global__ __launch_bounds__(256) void tobf_gather_kernel(const int* __restrict__ entity,
                                                          const float* __restrict__ emb,
                                                          u16* __restrict__ xbf, int n) {
    int idx = blockIdx.x * 256 + threadIdx.x;   // ushort4 index over n*32
    if (idx >= n * 32) return;
    int row = idx >> 5, c = idx & 31;
    float4 v = ((const float4*)emb)[(size_t)entity[row] * 32 + c];
    ushort4 o;
    o.x = f2bf(v.x); o.y = f2bf(v.y); o.z = f2bf(v.z); o.w = f2bf(v.w);
    ((ushort4*)xbf)[idx] = o;
}

// -------------------- CSR aggregation --------------------
__global__ __launch_bounds__(256) void agg_kernel(
    const int* __restrict__ row_start, const int* __restrict__ deg,
    const float* __restrict__ inv, const int* __restrict__ csr_src,
    const float4* __restrict__ csr_coef, const u16* __restrict__ xbf,
    u16* __restrict__ Zbf, int n)
{
    int nd = blockIdx.x * 8 + (threadIdx.x >> 5);
    if (nd >= n) return;
    int q = threadIdx.x & 31;
    int s0 = row_start[nd];
    int dg = deg[nd];
    float4 z0 = make_float4(0.f,0.f,0.f,0.f), z1 = z0, z2 = z0, z3 = z0;
    for (int i = 0; i < dg; ++i) {
        int s = csr_src[s0 + i];
        float4 c = csr_coef[s0 + i];
        ushort4 u = ((const ushort4*)xbf)[(size_t)s * 32 + q];
        float4 xv;
        xv.x = bf2f(u.x); xv.y = bf2f(u.y); xv.z = bf2f(u.z); xv.w = bf2f(u.w);
        z0.x += c.x * xv.x; z0.y += c.x * xv.y; z0.z += c.x * xv.z; z0.w += c.x * xv.w;
        z1.x += c.y * xv.x; z1.y += c.y * xv.y; z1.z += c.y * xv.z; z1.w += c.y * xv.w;
        z2.x += c.z * xv.x; z2.y += c.z * xv.y; z2.z += c.z * xv.z; z2.w += c.z * xv.w;
        z3.x += c.w * xv.x; z3.y += c.w * xv.y; z3.z += c.w * xv.z; z3.w += c.w * xv.w;
    }
    float iv = inv[nd];
    ushort4* zp = ((ushort4*)Zbf) + (size_t)nd * 128;   // [4][32] ushort4
    ushort4 o;
    o.x = f2bf(z0.x * iv); o.y = f2bf(z0.y * iv); o.z = f2bf(z0.z * iv); o.w = f2bf(z0.w * iv);
    zp[q] = o;
    o.x = f2bf(z1.x * iv); o.y = f2bf(z1.y * iv); o.z = f2bf(z1.z * iv); o.w = f2bf(z1.w * iv);
    zp[32 + q] = o;
    o.x = f2bf(z2.x * iv); o.y = f2bf(z2.y * iv); o.z = f2bf(z2.z * iv); o.w = f2bf(z2.w * iv);
    zp[64 + q] = o;
    o.x = f2bf(z3.x * iv); o.y = f2bf(z3.y * iv); o.z = f2bf(z3.z * iv); o.w = f2bf(z3.w * iv);
    zp[96 + q] = o;
}

// -------------------- weight prep: transpose + hi/lo bf16 split --------------------
__global__ __launch_bounds__(256) void wprep_kernel(
    const float* __restrict__ basis, const float* __restrict__ root,
    u16* __restrict__ Wt)
{
    int idx = blockIdx.x * 256 + threadIdx.x;  // over 640*128
    if (idx >= 640 * 128) return;
    int k = idx >> 7, nn = idx & 127;
    float w = (k < 512) ? basis[(size_t)k * 128 + nn] : root[(size_t)(k - 512) * 128 + nn];
    u16 hi = f2bf(w);
    float lo = w - bf2f(hi);
    Wt[(size_t)nn * 1280 + k] = hi;
    Wt[(size_t)nn * 1280 + 640 + k] = f2bf(lo);
}

// -------------------- MFMA layer GEMM --------------------
// out[M][128] = [Zbf | xbf](M x 640, bf16) @ W(640 x 128, hi+lo bf16) + bias
__global__ __launch_bounds__(256) void mfma_gemm_kernel(
    const u16* __restrict__ Zbf, const u16* __restrict__ xbf,
    const u16* __restrict__ Wt, const float* __restrict__ bias,
    int relu, int write_bf, u16* __restrict__ obf, float* __restrict__ of32, int n)
{
    __shared__ u16 As[BM][LDK];   // 18 KB
    __shared__ u16 Bs[BM][LDK];   // 18 KB (n-major: Bs[n][k])

    const int tid = threadIdx.x;
    const int row0 = blockIdx.x * BM;
    const int l  = tid & 63;
    const int w  = tid >> 6;
    const int wr = (w >> 1) * 64;   // wave row offset
    const int wc = (w & 1) * 64;    // wave col offset
    const int lr = l & 15;          // fragment M-row (A) / N-col (B)
    const int lk = l >> 4;          // k-group (0..3) -> k offset lk*8

    f32x4 zero = {0.f, 0.f, 0.f, 0.f};
    f32x4 acc[4][4];
#pragma unroll
    for (int mi = 0; mi < 4; ++mi)
#pragma unroll
        for (int ni = 0; ni < 4; ++ni) acc[mi][ni] = zero;

    for (int s = 0; s < 20; ++s) {
        const int ac = s >> 1;                     // A chunk 0..9
        const int wk = (s & 1) * 640 + ac * 64;    // Wt k-offset (hi then lo)
        __syncthreads();
        if ((s & 1) == 0) {
#pragma unroll
            for (int i = 0; i < 4; ++i) {
                int g = tid + i * 256;
                int r = g >> 3, sl = g & 7;
                int grow = row0 + r;
                uint4 v = make_uint4(0u, 0u, 0u, 0u);
                if (grow < n) {
                    const u16* p = (ac < 8)
                        ? (Zbf + (size_t)grow * 512 + ac * 64 + sl * 8)
                        : (xbf + (size_t)grow * 128 + (ac - 8) * 64 + sl * 8);
                    v = *(const uint4*)p;
                }
                *(uint4*)&As[r][sl * 8] = v;
            }
        }
#pragma unroll
        for (int i = 0; i < 4; ++i) {
            int g = tid + i * 256;
            int r = g >> 3, sl = g & 7;
            uint4 v = *(const uint4*)(Wt + (size_t)r * 1280 + wk + sl * 8);
            *(uint4*)&Bs[r][sl * 8] = v;
        }
        __syncthreads();

#pragma unroll
        for (int kh = 0; kh < 2; ++kh) {
            bf16x8 af[4], bfr[4];
#pragma unroll
            for (int mi = 0; mi < 4; ++mi)
                af[mi] = *(const bf16x8*)&As[wr + mi * 16 + lr][kh * 32 + lk * 8];
#pragma unroll
            for (int ni = 0; ni < 4; ++ni)
                bfr[ni] = *(const bf16x8*)&Bs[wc + ni * 16 + lr][kh * 32 + lk * 8];
#pragma unroll
            for (int mi = 0; mi < 4; ++mi)
#pragma unroll
                for (int ni = 0; ni < 4; ++ni)
                    acc[mi][ni] = __builtin_amdgcn_mfma_f32_16x16x32_bf16(
                        af[mi], bfr[ni], acc[mi][ni], 0, 0, 0);
        }
    }

    // epilogue: C/D layout col = lane&15, row = (lane>>4)*4 + reg
#pragma unroll
    for (int ni = 0; ni < 4; ++ni) {
        int col = wc + ni * 16 + lr;
        float bv = bias[col];
#pragma unroll
        for (int mi = 0; mi < 4; ++mi) {
#pragma unroll
            for (int r = 0; r < 4; ++r) {
                int row = row0 + wr + mi * 16 + lk * 4 + r;
                if (row < n) {
                    float v = acc[mi][ni][r] + bv;
                    if (relu) v = fmaxf(v, 0.f);
                    if (write_bf) obf[(size_t)row * 128 + col] = f2bf(v);
                    else          of32[(size_t)row * 128 + col] = v;
                }
            }
        }
    }
}

// -------------------- launch --------------------

extern "C" void kernel_launch(void* const* d_in, const int* in_sizes, int n_in,
                              void* d_out, int out_size, void* d_ws, size_t ws_size,
                              hipStream_t stream) {
    const int*   entity     = (const int*)d_in[0];
    const int*   edge_index = (const int*)d_in[1];
    const int*   edge_type  = (const int*)d_in[2];
    const float* edge_norm  = (const float*)d_in[3];
    const float* emb        = (const float*)d_in[4];
    const float* basis1     = (const float*)d_in[5];
    const float* att1       = (const float*)d_in[6];
    const float* root1      = (const float*)d_in[7];
    const float* bias1      = (const float*)d_in[8];
    const float* basis2     = (const float*)d_in[9];
    const float* att2       = (const float*)d_in[10];
    const float* root2      = (const float*)d_in[11];
    const float* bias2      = (const float*)d_in[12];
    float* out = (float*)d_out;

    const int N = in_sizes[0];
    const int E = in_sizes[2];
    const int* src = edge_index;
    const int* dst = edge_index + E;

    size_t ND = (size_t)N * D;
    char* wp = (char*)d_ws;
    int nb = (N + SCAN_B - 1) / SCAN_B;

    size_t off = 0;
    u16*    Zbf      = (u16*)(wp + off);   off += ND * 8;            // N*512 bf16
    u16*    xbf0     = (u16*)(wp + off);   off += ND * 2;            // N*128 bf16
    u16*    Wt       = (u16*)(wp + off);   off += (size_t)128 * 1280 * 2;
    float4* csr_coef = (float4*)(wp + off); off += (size_t)E * 16;
    int*    csr_src  = (int*)(wp + off);   off += (size_t)E * 4;
    int*    csr_eid  = (int*)(wp + off);   off += (size_t)E * 4;
    int*    deg      = (int*)(wp + off);   off += (size_t)N * 4;
    int*    fill     = (int*)(wp + off);   off += (size_t)N * 4;
    float*  inv      = (float*)(wp + off); off += (size_t)N * 4;
    int*    row_start= (int*)(wp + off);   off += (size_t)(N + 1) * 4;
    int*    bsum     = (int*)(wp + off);   off += (size_t)(nb + 1) * 4;
    size_t need = off;

    if (ws_size < need) {
        hipMemsetAsync(d_out, 0, (size_t)out_size * sizeof(float), stream);
        return;
    }

    u16* xbf1 = (u16*)d_out;   // bf16 scratch inside d_out; overwritten by final fp32 GEMM

    int eblk = (E + 255) / 256;
    int ablk = (N + 7) / 8;
    int gblk = (N * 32 + 255) / 256;
    int mblk = (N + BM - 1) / BM;
    int wblk = (640 * 128 + 255) / 256;
    int nblk256 = (N + 255) / 256;

    // ---- CSR build (once) ----
    hipMemsetAsync(deg, 0, (size_t)N * 4, stream);
    degree_int_kernel<<<eblk, 256, 0, stream>>>(dst, deg, E);
    scan1_kernel<<<nb, 256, 0, stream>>>(deg, row_start, bsum, N);
    scan2_kernel<<<1, 256, 0, stream>>>(bsum, nb);
    scan3_kernel<<<nblk256, 256, 0, stream>>>(deg, bsum, row_start, inv, N, E);
    hipMemsetAsync(fill, 0, (size_t)N * 4, stream);
    fill_kernel<<<eblk, 256, 0, stream>>>(src, dst, row_start, fill, csr_src, csr_eid, E);
    coef_kernel<<<eblk, 256, 0, stream>>>(csr_eid, edge_type, edge_norm, att1, csr_coef, E);
    tobf_gather_kernel<<<gblk, 256, 0, stream>>>(entity, emb, xbf0, N);
    wprep_kernel<<<wblk, 256, 0, stream>>>(basis1, root1, Wt);

    // ---- layer 1: xbf0 -> xbf1 ----
    agg_kernel<<<ablk, 256, 0, stream>>>(row_start, deg, inv, csr_src, csr_coef, xbf0, Zbf, N);
    mfma_gemm_kernel<<<mblk, 256, 0, stream>>>(Zbf, xbf0, Wt, bias1, 0, 1, xbf1, nullptr, N);

    // ---- layer 2: xbf1 -> xbf0 (relu) ----
    agg_kernel<<<ablk, 256, 0, stream>>>(row_start, deg, inv, csr_src, csr_coef, xbf1, Zbf, N);
    mfma_gemm_kernel<<<mblk, 256, 0, stream>>>(Zbf, xbf1, Wt, bias1, 1, 1, xbf0, nullptr, N);

    // ---- layer 3: new coef (att2) + new weights; xbf0 -> out (fp32) ----
    coef_kernel<<<eblk, 256, 0, stream>>>(csr_eid, edge_type, edge_norm, att2, csr_coef, E);
    wprep_kernel<<<wblk, 256, 0, stream>>>(basis2, root2, Wt);
    agg_kernel<<<ablk, 256, 0, stream>>>(row_start, deg, inv, csr_src, csr_coef, xbf0, Zbf, N);
    mfma_gemm_kernel<<<mblk, 256, 0, stream>>>(Zbf, xbf0, Wt, bias2, 0, 0, nullptr, out, N);
}

// Round 6
// 517.970 us; speedup vs baseline: 9.6998x; 1.1804x over previous
//
#include <hip/hip_runtime.h>

#define D 128
#define NB 4
#define BM2 256
#define SCAN_B 1024

typedef unsigned short u16;
typedef unsigned int u32;
using bf16x8 = __attribute__((ext_vector_type(8))) short;
using f32x4  = __attribute__((ext_vector_type(4))) float;

__device__ __forceinline__ float bf2f(u16 u) {
    union { u32 i; float f; } v; v.i = ((u32)u) << 16; return v.f;
}
__device__ __forceinline__ u16 f2bf(float f) {
    union { float ff; u32 i; } v; v.ff = f;
    u32 r = v.i + 0x7fffu + ((v.i >> 16) & 1u);   // RNE
    return (u16)(r >> 16);
}

// async 16B global -> LDS (wave-uniform lds base; lane i writes base + i*16)
__device__ __forceinline__ void async16(void* lds, const void* g) {
    __builtin_amdgcn_global_load_lds(
        (const __attribute__((address_space(1))) unsigned int*)g,
        (__attribute__((address_space(3))) unsigned int*)lds,
        16, 0, 0);
}

// -------------------- CSR build --------------------

__global__ __launch_bounds__(256) void degree_int_kernel(const int* __restrict__ dst,
                                                         int* __restrict__ deg, int E) {
    int e = blockIdx.x * 256 + threadIdx.x;
    if (e < E) atomicAdd(&deg[dst[e]], 1);
}

__global__ __launch_bounds__(256) void scan1_kernel(const int* __restrict__ deg,
                                                    int* __restrict__ row_start,
                                                    int* __restrict__ bsum, int n) {
    __shared__ int tsum[256];
    int base = blockIdx.x * SCAN_B;
    int t = threadIdx.x;
    int v[4];
    int s = 0;
#pragma unroll
    for (int i = 0; i < 4; ++i) {
        int idx = base + t * 4 + i;
        v[i] = (idx < n) ? deg[idx] : 0;
        s += v[i];
    }
    tsum[t] = s;
    __syncthreads();
    for (int off = 1; off < 256; off <<= 1) {
        int x = (t >= off) ? tsum[t - off] : 0;
        __syncthreads();
        tsum[t] += x;
        __syncthreads();
    }
    int run = tsum[t] - s;
#pragma unroll
    for (int i = 0; i < 4; ++i) {
        int idx = base + t * 4 + i;
        if (idx < n) row_start[idx] = run;
        run += v[i];
    }
    if (t == 255) bsum[blockIdx.x] = tsum[255];
}

__global__ __launch_bounds__(256) void scan2_kernel(int* __restrict__ bsum, int nb) {
    __shared__ int buf[256];
    __shared__ int carry_s;
    if (threadIdx.x == 0) carry_s = 0;
    __syncthreads();
    for (int base = 0; base < nb; base += 256) {
        int i = base + threadIdx.x;
        int v = (i < nb) ? bsum[i] : 0;
        buf[threadIdx.x] = v;
        __syncthreads();
        for (int off = 1; off < 256; off <<= 1) {
            int x = (threadIdx.x >= (unsigned)off) ? buf[threadIdx.x - off] : 0;
            __syncthreads();
            buf[threadIdx.x] += x;
            __syncthreads();
        }
        if (i < nb) bsum[i] = carry_s + buf[threadIdx.x] - v;
        __syncthreads();
        if (threadIdx.x == 0) carry_s += buf[255];
        __syncthreads();
    }
}

__global__ __launch_bounds__(256) void scan3_kernel(const int* __restrict__ deg,
                                                    const int* __restrict__ bsum,
                                                    int* __restrict__ row_start,
                                                    float* __restrict__ inv, int n, int E) {
    int i = blockIdx.x * 256 + threadIdx.x;
    if (i < n) {
        row_start[i] += bsum[i >> 10];
        inv[i] = 1.0f / fmaxf((float)deg[i], 1.0f);
    }
    if (i == 0) row_start[n] = E;
}

__global__ __launch_bounds__(256) void fill_kernel(
    const int* __restrict__ src, const int* __restrict__ dst,
    const int* __restrict__ row_start, int* __restrict__ fill,
    int* __restrict__ csr_src, int* __restrict__ csr_eid, int E)
{
    int e = blockIdx.x * 256 + threadIdx.x;
    if (e >= E) return;
    int d0 = dst[e];
    int pos = row_start[d0] + atomicAdd(&fill[d0], 1);
    csr_src[pos] = src[e];
    csr_eid[pos] = e;
}

__global__ __launch_bounds__(256) void coef_kernel(
    const int* __restrict__ csr_eid, const int* __restrict__ etype,
    const float* __restrict__ norm, const float* __restrict__ att,
    float4* __restrict__ csr_coef, int E)
{
    int p = blockIdx.x * 256 + threadIdx.x;
    if (p >= E) return;
    int e = csr_eid[p];
    float nm = norm[e];
    float4 a = ((const float4*)att)[etype[e]];
    csr_coef[p] = make_float4(a.x * nm, a.y * nm, a.z * nm, a.w * nm);
}

// -------------------- gather emb -> bf16 x0 --------------------

__global__ __launch_bounds__(256) void tobf_gather_kernel(const int* __restrict__ entity,
                                                          const float* __restrict__ emb,
                                                          u16* __restrict__ xbf, int n) {
    int idx = blockIdx.x * 256 + threadIdx.x;
    if (idx >= n * 32) return;
    int row = idx >> 5, c = idx & 31;
    float4 v = ((const float4*)emb)[(size_t)entity[row] * 32 + c];
    ushort4 o;
    o.x = f2bf(v.x); o.y = f2bf(v.y); o.z = f2bf(v.z); o.w = f2bf(v.w);
    ((ushort4*)xbf)[idx] = o;
}

// -------------------- CSR aggregation --------------------
__global__ __launch_bounds__(256) void agg_kernel(
    const int* __restrict__ row_start, const int* __restrict__ deg,
    const float* __restrict__ inv, const int* __restrict__ csr_src,
    const float4* __restrict__ csr_coef, const u16* __restrict__ xbf,
    u16* __restrict__ Zbf, int n)
{
    int nd = blockIdx.x * 8 + (threadIdx.x >> 5);
    if (nd >= n) return;
    int q = threadIdx.x & 31;
    int s0 = row_start[nd];
    int dg = deg[nd];
    float4 z0 = make_float4(0.f,0.f,0.f,0.f), z1 = z0, z2 = z0, z3 = z0;
    for (int i = 0; i < dg; ++i) {
        int s = csr_src[s0 + i];
        float4 c = csr_coef[s0 + i];
        ushort4 u = ((const ushort4*)xbf)[(size_t)s * 32 + q];
        float4 xv;
        xv.x = bf2f(u.x); xv.y = bf2f(u.y); xv.z = bf2f(u.z); xv.w = bf2f(u.w);
        z0.x += c.x * xv.x; z0.y += c.x * xv.y; z0.z += c.x * xv.z; z0.w += c.x * xv.w;
        z1.x += c.y * xv.x; z1.y += c.y * xv.y; z1.z += c.y * xv.z; z1.w += c.y * xv.w;
        z2.x += c.z * xv.x; z2.y += c.z * xv.y; z2.z += c.z * xv.z; z2.w += c.z * xv.w;
        z3.x += c.w * xv.x; z3.y += c.w * xv.y; z3.z += c.w * xv.z; z3.w += c.w * xv.w;
    }
    float iv = inv[nd];
    ushort4* zp = ((ushort4*)Zbf) + (size_t)nd * 128;
    ushort4 o;
    o.x = f2bf(z0.x * iv); o.y = f2bf(z0.y * iv); o.z = f2bf(z0.z * iv); o.w = f2bf(z0.w * iv);
    zp[q] = o;
    o.x = f2bf(z1.x * iv); o.y = f2bf(z1.y * iv); o.z = f2bf(z1.z * iv); o.w = f2bf(z1.w * iv);
    zp[32 + q] = o;
    o.x = f2bf(z2.x * iv); o.y = f2bf(z2.y * iv); o.z = f2bf(z2.z * iv); o.w = f2bf(z2.w * iv);
    zp[64 + q] = o;
    o.x = f2bf(z3.x * iv); o.y = f2bf(z3.y * iv); o.z = f2bf(z3.z * iv); o.w = f2bf(z3.w * iv);
    zp[96 + q] = o;
}

// -------------------- weight prep: transpose + hi/lo bf16 split --------------------
__global__ __launch_bounds__(256) void wprep_kernel(
    const float* __restrict__ basis, const float* __restrict__ root,
    u16* __restrict__ Wt)
{
    int idx = blockIdx.x * 256 + threadIdx.x;  // over 640*128
    if (idx >= 640 * 128) return;
    int k = idx >> 7, nn = idx & 127;
    float w = (k < 512) ? basis[(size_t)k * 128 + nn] : root[(size_t)(k - 512) * 128 + nn];
    u16 hi = f2bf(w);
    float lo = w - bf2f(hi);
    Wt[(size_t)nn * 1280 + k] = hi;
    Wt[(size_t)nn * 1280 + 640 + k] = f2bf(lo);
}

// -------------------- MFMA layer GEMM (256x128 tile, 8 waves) --------------------
// out[M][128] = [Zbf | xbf](M x 640 bf16) @ W(640 x 128, hi+lo bf16) + bias
// LDS: linear rows of 128B, content XOR-swizzled via pre-swizzled GLOBAL source
// (global_load_lds writes lane i at base+i*16); reads apply the same XOR.
__global__ __launch_bounds__(512) void mfma_gemm_kernel(
    const u16* __restrict__ Zbf, const u16* __restrict__ xbf,
    const u16* __restrict__ Wt, const float* __restrict__ bias,
    int relu, int write_bf, u16* __restrict__ obf, float* __restrict__ of32, int n)
{
    __shared__ u16 As[BM2 * 64];   // 32 KB
    __shared__ u16 Bs[128 * 64];   // 16 KB

    const int tid  = threadIdx.x;
    const int row0 = blockIdx.x * BM2;
    const int lane = tid & 63;
    const int w    = tid >> 6;        // 0..7
    const int wr   = (w >> 1) * 64;   // 0,64,128,192
    const int wc   = (w & 1) * 64;    // 0,64
    const int lr   = lane & 15;
    const int lk   = lane >> 4;

    const int srow = lane >> 3;                      // r & 7 for staging
    const int sswz = ((lane & 7) * 16) ^ (srow << 4); // swizzled byte within row

    f32x4 zero = {0.f, 0.f, 0.f, 0.f};
    f32x4 acc[4][4];
#pragma unroll
    for (int mi = 0; mi < 4; ++mi)
#pragma unroll
        for (int ni = 0; ni < 4; ++ni) acc[mi][ni] = zero;

    for (int s = 0; s < 20; ++s) {
        const int ac = s >> 1;                    // A chunk 0..9
        const int wk = (s & 1) * 640 + ac * 64;   // Wt k-offset (hi then lo)
        __syncthreads();
        if ((s & 1) == 0) {
            // stage A: 256 rows x 128B; wave w rows 32w..32w+31, 4 instrs
#pragma unroll
            for (int j = 0; j < 4; ++j) {
                int r    = (w << 5) + (j << 3) + srow;
                int grow = row0 + r;
                const u16* gp = (ac < 8)
                    ? (Zbf + (size_t)grow * 512 + ac * 64)
                    : (xbf + (size_t)grow * 128 + (ac - 8) * 64);
                async16((char*)As + (((w << 5) + (j << 3)) << 7),
                        (const char*)gp + sswz);
            }
        }
        // stage B: 128 rows x 128B; wave w rows 16w..16w+15, 2 instrs
#pragma unroll
        for (int j = 0; j < 2; ++j) {
            int rr = (w << 4) + (j << 3) + srow;
            const u16* gp = Wt + (size_t)rr * 1280 + wk;
            async16((char*)Bs + (((w << 4) + (j << 3)) << 7),
                    (const char*)gp + sswz);
        }
        __syncthreads();   // compiler drains vmcnt before barrier -> LDS ready

#pragma unroll
        for (int kh = 0; kh < 2; ++kh) {
            const int kb = (kh * 64 + lk * 16) ^ ((lr & 7) << 4);
            bf16x8 af[4], bfr[4];
#pragma unroll
            for (int mi = 0; mi < 4; ++mi)
                af[mi] = *(const bf16x8*)((const char*)As + ((wr + mi * 16 + lr) << 7) + kb);
#pragma unroll
            for (int ni = 0; ni < 4; ++ni)
                bfr[ni] = *(const bf16x8*)((const char*)Bs + ((wc + ni * 16 + lr) << 7) + kb);
#pragma unroll
            for (int mi = 0; mi < 4; ++mi)
#pragma unroll
                for (int ni = 0; ni < 4; ++ni)
                    acc[mi][ni] = __builtin_amdgcn_mfma_f32_16x16x32_bf16(
                        af[mi], bfr[ni], acc[mi][ni], 0, 0, 0);
        }
    }

    // epilogue: C/D layout col = lane&15, row = (lane>>4)*4 + reg
#pragma unroll
    for (int ni = 0; ni < 4; ++ni) {
        int col = wc + ni * 16 + lr;
        float bv = bias[col];
#pragma unroll
        for (int mi = 0; mi < 4; ++mi) {
#pragma unroll
            for (int r = 0; r < 4; ++r) {
                int row = row0 + wr + mi * 16 + lk * 4 + r;
                if (row < n) {
                    float v = acc[mi][ni][r] + bv;
                    if (relu) v = fmaxf(v, 0.f);
                    if (write_bf) obf[(size_t)row * 128 + col] = f2bf(v);
                    else          of32[(size_t)row * 128 + col] = v;
                }
            }
        }
    }
}

// -------------------- launch --------------------

extern "C" void kernel_launch(void* const* d_in, const int* in_sizes, int n_in,
                              void* d_out, int out_size, void* d_ws, size_t ws_size,
                              hipStream_t stream) {
    const int*   entity     = (const int*)d_in[0];
    const int*   edge_index = (const int*)d_in[1];
    const int*   edge_type  = (const int*)d_in[2];
    const float* edge_norm  = (const float*)d_in[3];
    const float* emb        = (const float*)d_in[4];
    const float* basis1     = (const float*)d_in[5];
    const float* att1       = (const float*)d_in[6];
    const float* root1      = (const float*)d_in[7];
    const float* bias1      = (const float*)d_in[8];
    const float* basis2     = (const float*)d_in[9];
    const float* att2       = (const float*)d_in[10];
    const float* root2      = (const float*)d_in[11];
    const float* bias2      = (const float*)d_in[12];
    float* out = (float*)d_out;

    const int N = in_sizes[0];
    const int E = in_sizes[2];
    const int* src = edge_index;
    const int* dst = edge_index + E;

    size_t ND = (size_t)N * D;
    char* wp = (char*)d_ws;
    int nb = (N + SCAN_B - 1) / SCAN_B;

    size_t off = 0;
    u16*    Zbf      = (u16*)(wp + off);   off += ND * 8;            // N*512 bf16
    u16*    xbf0     = (u16*)(wp + off);   off += ND * 2;            // N*128 bf16
    u16*    Wt       = (u16*)(wp + off);   off += (size_t)128 * 1280 * 2;
    float4* csr_coef = (float4*)(wp + off); off += (size_t)E * 16;
    int*    csr_src  = (int*)(wp + off);   off += (size_t)E * 4;
    int*    csr_eid  = (int*)(wp + off);   off += (size_t)E * 4;
    int*    deg      = (int*)(wp + off);   off += (size_t)N * 4;
    int*    fill     = (int*)(wp + off);   off += (size_t)N * 4;
    float*  inv      = (float*)(wp + off); off += (size_t)N * 4;
    int*    row_start= (int*)(wp + off);   off += (size_t)(N + 1) * 4;
    int*    bsum     = (int*)(wp + off);   off += (size_t)(nb + 1) * 4;
    size_t need = off;

    if (ws_size < need) {
        hipMemsetAsync(d_out, 0, (size_t)out_size * sizeof(float), stream);
        return;
    }

    u16* xbf1 = (u16*)d_out;   // bf16 scratch inside d_out; overwritten by final fp32 GEMM

    int eblk = (E + 255) / 256;
    int ablk = (N + 7) / 8;
    int gblk = (N * 32 + 255) / 256;
    int mblk = (N + BM2 - 1) / BM2;
    int wblk = (640 * 128 + 255) / 256;
    int nblk256 = (N + 255) / 256;

    // ---- CSR build (once) ----
    hipMemsetAsync(deg, 0, (size_t)N * 4, stream);
    degree_int_kernel<<<eblk, 256, 0, stream>>>(dst, deg, E);
    scan1_kernel<<<nb, 256, 0, stream>>>(deg, row_start, bsum, N);
    scan2_kernel<<<1, 256, 0, stream>>>(bsum, nb);
    scan3_kernel<<<nblk256, 256, 0, stream>>>(deg, bsum, row_start, inv, N, E);
    hipMemsetAsync(fill, 0, (size_t)N * 4, stream);
    fill_kernel<<<eblk, 256, 0, stream>>>(src, dst, row_start, fill, csr_src, csr_eid, E);
    coef_kernel<<<eblk, 256, 0, stream>>>(csr_eid, edge_type, edge_norm, att1, csr_coef, E);
    tobf_gather_kernel<<<gblk, 256, 0, stream>>>(entity, emb, xbf0, N);
    wprep_kernel<<<wblk, 256, 0, stream>>>(basis1, root1, Wt);

    // ---- layer 1: xbf0 -> xbf1 ----
    agg_kernel<<<ablk, 256, 0, stream>>>(row_start, deg, inv, csr_src, csr_coef, xbf0, Zbf, N);
    mfma_gemm_kernel<<<mblk, 512, 0, stream>>>(Zbf, xbf0, Wt, bias1, 0, 1, xbf1, nullptr, N);

    // ---- layer 2: xbf1 -> xbf0 (relu) ----
    agg_kernel<<<ablk, 256, 0, stream>>>(row_start, deg, inv, csr_src, csr_coef, xbf1, Zbf, N);
    mfma_gemm_kernel<<<mblk, 512, 0, stream>>>(Zbf, xbf1, Wt, bias1, 1, 1, xbf0, nullptr, N);

    // ---- layer 3: new coef (att2) + new weights; xbf0 -> out (fp32) ----
    coef_kernel<<<eblk, 256, 0, stream>>>(csr_eid, edge_type, edge_norm, att2, csr_coef, E);
    wprep_kernel<<<wblk, 256, 0, stream>>>(basis2, root2, Wt);
    agg_kernel<<<ablk, 256, 0, stream>>>(row_start, deg, inv, csr_src, csr_coef, xbf0, Zbf, N);
    mfma_gemm_kernel<<<mblk, 512, 0, stream>>>(Zbf, xbf0, Wt, bias2, 0, 0, nullptr, out, N);
}

// Round 7
// 465.507 us; speedup vs baseline: 10.7930x; 1.1127x over previous
//
#include <hip/hip_runtime.h>

#define D 128
#define NB 4
#define BM2 256
#define SCAN_B 1024

typedef unsigned short u16;
typedef unsigned int u32;
using bf16x8 = __attribute__((ext_vector_type(8))) short;
using f32x4  = __attribute__((ext_vector_type(4))) float;

__device__ __forceinline__ float bf2f(u16 u) {
    union { u32 i; float f; } v; v.i = ((u32)u) << 16; return v.f;
}
__device__ __forceinline__ u16 f2bf(float f) {
    union { float ff; u32 i; } v; v.ff = f;
    u32 r = v.i + 0x7fffu + ((v.i >> 16) & 1u);   // RNE
    return (u16)(r >> 16);
}

// async 16B global -> LDS (wave-uniform lds base; lane i writes base + i*16)
__device__ __forceinline__ void async16(void* lds, const void* g) {
    __builtin_amdgcn_global_load_lds(
        (const __attribute__((address_space(1))) unsigned int*)g,
        (__attribute__((address_space(3))) unsigned int*)lds,
        16, 0, 0);
}

// -------------------- CSR build --------------------

__global__ __launch_bounds__(256) void degree_int_kernel(const int* __restrict__ dst,
                                                         int* __restrict__ deg, int E) {
    int e = blockIdx.x * 256 + threadIdx.x;
    if (e < E) atomicAdd(&deg[dst[e]], 1);
}

__global__ __launch_bounds__(256) void scan1_kernel(const int* __restrict__ deg,
                                                    int* __restrict__ row_start,
                                                    int* __restrict__ bsum, int n) {
    __shared__ int tsum[256];
    int base = blockIdx.x * SCAN_B;
    int t = threadIdx.x;
    int v[4];
    int s = 0;
#pragma unroll
    for (int i = 0; i < 4; ++i) {
        int idx = base + t * 4 + i;
        v[i] = (idx < n) ? deg[idx] : 0;
        s += v[i];
    }
    tsum[t] = s;
    __syncthreads();
    for (int off = 1; off < 256; off <<= 1) {
        int x = (t >= off) ? tsum[t - off] : 0;
        __syncthreads();
        tsum[t] += x;
        __syncthreads();
    }
    int run = tsum[t] - s;
#pragma unroll
    for (int i = 0; i < 4; ++i) {
        int idx = base + t * 4 + i;
        if (idx < n) row_start[idx] = run;
        run += v[i];
    }
    if (t == 255) bsum[blockIdx.x] = tsum[255];
}

__global__ __launch_bounds__(256) void scan2_kernel(int* __restrict__ bsum, int nb) {
    __shared__ int buf[256];
    __shared__ int carry_s;
    if (threadIdx.x == 0) carry_s = 0;
    __syncthreads();
    for (int base = 0; base < nb; base += 256) {
        int i = base + threadIdx.x;
        int v = (i < nb) ? bsum[i] : 0;
        buf[threadIdx.x] = v;
        __syncthreads();
        for (int off = 1; off < 256; off <<= 1) {
            int x = (threadIdx.x >= (unsigned)off) ? buf[threadIdx.x - off] : 0;
            __syncthreads();
            buf[threadIdx.x] += x;
            __syncthreads();
        }
        if (i < nb) bsum[i] = carry_s + buf[threadIdx.x] - v;
        __syncthreads();
        if (threadIdx.x == 0) carry_s += buf[255];
        __syncthreads();
    }
}

__global__ __launch_bounds__(256) void scan3_kernel(const int* __restrict__ deg,
                                                    const int* __restrict__ bsum,
                                                    int* __restrict__ row_start,
                                                    float* __restrict__ inv, int n, int E) {
    int i = blockIdx.x * 256 + threadIdx.x;
    if (i < n) {
        row_start[i] += bsum[i >> 10];
        inv[i] = 1.0f / fmaxf((float)deg[i], 1.0f);
    }
    if (i == 0) row_start[n] = E;
}

__global__ __launch_bounds__(256) void fill_kernel(
    const int* __restrict__ src, const int* __restrict__ dst,
    const int* __restrict__ row_start, int* __restrict__ fill,
    int* __restrict__ csr_src, int* __restrict__ csr_eid, int E)
{
    int e = blockIdx.x * 256 + threadIdx.x;
    if (e >= E) return;
    int d0 = dst[e];
    int pos = row_start[d0] + atomicAdd(&fill[d0], 1);
    csr_src[pos] = src[e];
    csr_eid[pos] = e;
}

__global__ __launch_bounds__(256) void coef_kernel(
    const int* __restrict__ csr_eid, const int* __restrict__ etype,
    const float* __restrict__ norm, const float* __restrict__ att,
    float4* __restrict__ csr_coef, int E)
{
    int p = blockIdx.x * 256 + threadIdx.x;
    if (p >= E) return;
    int e = csr_eid[p];
    float nm = norm[e];
    float4 a = ((const float4*)att)[etype[e]];
    csr_coef[p] = make_float4(a.x * nm, a.y * nm, a.z * nm, a.w * nm);
}

// -------------------- gather emb -> bf16 x0 --------------------

__global__ __launch_bounds__(256) void tobf_gather_kernel(const int* __restrict__ entity,
                                                          const float* __restrict__ emb,
                                                          u16* __restrict__ xbf, int n) {
    int idx = blockIdx.x * 256 + threadIdx.x;
    if (idx >= n * 32) return;
    int row = idx >> 5, c = idx & 31;
    float4 v = ((const float4*)emb)[(size_t)entity[row] * 32 + c];
    ushort4 o;
    o.x = f2bf(v.x); o.y = f2bf(v.y); o.z = f2bf(v.z); o.w = f2bf(v.w);
    ((ushort4*)xbf)[idx] = o;
}

// -------------------- CSR aggregation (4x unrolled for gather MLP) ----------
__global__ __launch_bounds__(256) void agg_kernel(
    const int* __restrict__ row_start, const int* __restrict__ deg,
    const float* __restrict__ inv, const int* __restrict__ csr_src,
    const float4* __restrict__ csr_coef, const u16* __restrict__ xbf,
    u16* __restrict__ Zbf, int n)
{
    int nd = blockIdx.x * 8 + (threadIdx.x >> 5);
    if (nd >= n) return;
    int q = threadIdx.x & 31;
    int s0 = row_start[nd];
    int dg = deg[nd];
    float4 z0 = make_float4(0.f,0.f,0.f,0.f), z1 = z0, z2 = z0, z3 = z0;

    int i = 0;
    for (; i + 4 <= dg; i += 4) {
        int s_[4];
        float4 c_[4];
        ushort4 u_[4];
#pragma unroll
        for (int j = 0; j < 4; ++j) s_[j] = csr_src[s0 + i + j];
#pragma unroll
        for (int j = 0; j < 4; ++j) c_[j] = csr_coef[s0 + i + j];
#pragma unroll
        for (int j = 0; j < 4; ++j) u_[j] = ((const ushort4*)xbf)[(size_t)s_[j] * 32 + q];
#pragma unroll
        for (int j = 0; j < 4; ++j) {
            float4 c = c_[j];
            float4 xv;
            xv.x = bf2f(u_[j].x); xv.y = bf2f(u_[j].y);
            xv.z = bf2f(u_[j].z); xv.w = bf2f(u_[j].w);
            z0.x += c.x * xv.x; z0.y += c.x * xv.y; z0.z += c.x * xv.z; z0.w += c.x * xv.w;
            z1.x += c.y * xv.x; z1.y += c.y * xv.y; z1.z += c.y * xv.z; z1.w += c.y * xv.w;
            z2.x += c.z * xv.x; z2.y += c.z * xv.y; z2.z += c.z * xv.z; z2.w += c.z * xv.w;
            z3.x += c.w * xv.x; z3.y += c.w * xv.y; z3.z += c.w * xv.z; z3.w += c.w * xv.w;
        }
    }
    for (; i < dg; ++i) {
        int s = csr_src[s0 + i];
        float4 c = csr_coef[s0 + i];
        ushort4 u = ((const ushort4*)xbf)[(size_t)s * 32 + q];
        float4 xv;
        xv.x = bf2f(u.x); xv.y = bf2f(u.y); xv.z = bf2f(u.z); xv.w = bf2f(u.w);
        z0.x += c.x * xv.x; z0.y += c.x * xv.y; z0.z += c.x * xv.z; z0.w += c.x * xv.w;
        z1.x += c.y * xv.x; z1.y += c.y * xv.y; z1.z += c.y * xv.z; z1.w += c.y * xv.w;
        z2.x += c.z * xv.x; z2.y += c.z * xv.y; z2.z += c.z * xv.z; z2.w += c.z * xv.w;
        z3.x += c.w * xv.x; z3.y += c.w * xv.y; z3.z += c.w * xv.z; z3.w += c.w * xv.w;
    }

    float iv = inv[nd];
    ushort4* zp = ((ushort4*)Zbf) + (size_t)nd * 128;
    ushort4 o;
    o.x = f2bf(z0.x * iv); o.y = f2bf(z0.y * iv); o.z = f2bf(z0.z * iv); o.w = f2bf(z0.w * iv);
    zp[q] = o;
    o.x = f2bf(z1.x * iv); o.y = f2bf(z1.y * iv); o.z = f2bf(z1.z * iv); o.w = f2bf(z1.w * iv);
    zp[32 + q] = o;
    o.x = f2bf(z2.x * iv); o.y = f2bf(z2.y * iv); o.z = f2bf(z2.z * iv); o.w = f2bf(z2.w * iv);
    zp[64 + q] = o;
    o.x = f2bf(z3.x * iv); o.y = f2bf(z3.y * iv); o.z = f2bf(z3.z * iv); o.w = f2bf(z3.w * iv);
    zp[96 + q] = o;
}

// -------------------- weight prep: transpose + hi/lo bf16 split --------------------
__global__ __launch_bounds__(256) void wprep_kernel(
    const float* __restrict__ basis, const float* __restrict__ root,
    u16* __restrict__ Wt)
{
    int idx = blockIdx.x * 256 + threadIdx.x;  // over 640*128
    if (idx >= 640 * 128) return;
    int k = idx >> 7, nn = idx & 127;
    float w = (k < 512) ? basis[(size_t)k * 128 + nn] : root[(size_t)(k - 512) * 128 + nn];
    u16 hi = f2bf(w);
    float lo = w - bf2f(hi);
    Wt[(size_t)nn * 1280 + k] = hi;
    Wt[(size_t)nn * 1280 + 640 + k] = f2bf(lo);
}

// -------------------- MFMA layer GEMM (256x128 tile, 8 waves) --------------------
__global__ __launch_bounds__(512) void mfma_gemm_kernel(
    const u16* __restrict__ Zbf, const u16* __restrict__ xbf,
    const u16* __restrict__ Wt, const float* __restrict__ bias,
    int relu, int write_bf, u16* __restrict__ obf, float* __restrict__ of32, int n)
{
    __shared__ u16 As[BM2 * 64];   // 32 KB
    __shared__ u16 Bs[128 * 64];   // 16 KB

    const int tid  = threadIdx.x;
    const int row0 = blockIdx.x * BM2;
    const int lane = tid & 63;
    const int w    = tid >> 6;        // 0..7
    const int wr   = (w >> 1) * 64;   // 0,64,128,192
    const int wc   = (w & 1) * 64;    // 0,64
    const int lr   = lane & 15;
    const int lk   = lane >> 4;

    const int srow = lane >> 3;                       // r & 7 for staging
    const int sswz = ((lane & 7) * 16) ^ (srow << 4); // swizzled byte within row

    f32x4 zero = {0.f, 0.f, 0.f, 0.f};
    f32x4 acc[4][4];
#pragma unroll
    for (int mi = 0; mi < 4; ++mi)
#pragma unroll
        for (int ni = 0; ni < 4; ++ni) acc[mi][ni] = zero;

    for (int s = 0; s < 20; ++s) {
        const int ac = s >> 1;                    // A chunk 0..9
        const int wk = (s & 1) * 640 + ac * 64;   // Wt k-offset (hi then lo)
        __syncthreads();
        if ((s & 1) == 0) {
#pragma unroll
            for (int j = 0; j < 4; ++j) {
                int r    = (w << 5) + (j << 3) + srow;
                int grow = row0 + r;
                const u16* gp = (ac < 8)
                    ? (Zbf + (size_t)grow * 512 + ac * 64)
                    : (xbf + (size_t)grow * 128 + (ac - 8) * 64);
                async16((char*)As + (((w << 5) + (j << 3)) << 7),
                        (const char*)gp + sswz);
            }
        }
#pragma unroll
        for (int j = 0; j < 2; ++j) {
            int rr = (w << 4) + (j << 3) + srow;
            const u16* gp = Wt + (size_t)rr * 1280 + wk;
            async16((char*)Bs + (((w << 4) + (j << 3)) << 7),
                    (const char*)gp + sswz);
        }
        __syncthreads();

#pragma unroll
        for (int kh = 0; kh < 2; ++kh) {
            const int kb = (kh * 64 + lk * 16) ^ ((lr & 7) << 4);
            bf16x8 af[4], bfr[4];
#pragma unroll
            for (int mi = 0; mi < 4; ++mi)
                af[mi] = *(const bf16x8*)((const char*)As + ((wr + mi * 16 + lr) << 7) + kb);
#pragma unroll
            for (int ni = 0; ni < 4; ++ni)
                bfr[ni] = *(const bf16x8*)((const char*)Bs + ((wc + ni * 16 + lr) << 7) + kb);
#pragma unroll
            for (int mi = 0; mi < 4; ++mi)
#pragma unroll
                for (int ni = 0; ni < 4; ++ni)
                    acc[mi][ni] = __builtin_amdgcn_mfma_f32_16x16x32_bf16(
                        af[mi], bfr[ni], acc[mi][ni], 0, 0, 0);
        }
    }

#pragma unroll
    for (int ni = 0; ni < 4; ++ni) {
        int col = wc + ni * 16 + lr;
        float bv = bias[col];
#pragma unroll
        for (int mi = 0; mi < 4; ++mi) {
#pragma unroll
            for (int r = 0; r < 4; ++r) {
                int row = row0 + wr + mi * 16 + lk * 4 + r;
                if (row < n) {
                    float v = acc[mi][ni][r] + bv;
                    if (relu) v = fmaxf(v, 0.f);
                    if (write_bf) obf[(size_t)row * 128 + col] = f2bf(v);
                    else          of32[(size_t)row * 128 + col] = v;
                }
            }
        }
    }
}

// -------------------- launch --------------------

extern "C" void kernel_launch(void* const* d_in, const int* in_sizes, int n_in,
                              void* d_out, int out_size, void* d_ws, size_t ws_size,
                              hipStream_t stream) {
    const int*   entity     = (const int*)d_in[0];
    const int*   edge_index = (const int*)d_in[1];
    const int*   edge_type  = (const int*)d_in[2];
    const float* edge_norm  = (const float*)d_in[3];
    const float* emb        = (const float*)d_in[4];
    const float* basis1     = (const float*)d_in[5];
    const float* att1       = (const float*)d_in[6];
    const float* root1      = (const float*)d_in[7];
    const float* bias1      = (const float*)d_in[8];
    const float* basis2     = (const float*)d_in[9];
    const float* att2       = (const float*)d_in[10];
    const float* root2      = (const float*)d_in[11];
    const float* bias2      = (const float*)d_in[12];
    float* out = (float*)d_out;

    const int N = in_sizes[0];
    const int E = in_sizes[2];
    const int* src = edge_index;
    const int* dst = edge_index + E;

    size_t ND = (size_t)N * D;
    char* wp = (char*)d_ws;
    int nb = (N + SCAN_B - 1) / SCAN_B;

    size_t off = 0;
    u16*    Zbf      = (u16*)(wp + off);   off += ND * 8;            // N*512 bf16
    u16*    xbf0     = (u16*)(wp + off);   off += ND * 2;            // N*128 bf16
    u16*    Wt       = (u16*)(wp + off);   off += (size_t)128 * 1280 * 2;
    float4* csr_coef = (float4*)(wp + off); off += (size_t)E * 16;
    int*    csr_src  = (int*)(wp + off);   off += (size_t)E * 4;
    int*    csr_eid  = (int*)(wp + off);   off += (size_t)E * 4;
    int*    deg      = (int*)(wp + off);   off += (size_t)N * 4;
    int*    fill     = (int*)(wp + off);   off += (size_t)N * 4;
    float*  inv      = (float*)(wp + off); off += (size_t)N * 4;
    int*    row_start= (int*)(wp + off);   off += (size_t)(N + 1) * 4;
    int*    bsum     = (int*)(wp + off);   off += (size_t)(nb + 1) * 4;
    size_t need = off;

    if (ws_size < need) {
        hipMemsetAsync(d_out, 0, (size_t)out_size * sizeof(float), stream);
        return;
    }

    u16* xbf1 = (u16*)d_out;   // bf16 scratch inside d_out; overwritten by final fp32 GEMM

    int eblk = (E + 255) / 256;
    int ablk = (N + 7) / 8;
    int gblk = (N * 32 + 255) / 256;
    int mblk = (N + BM2 - 1) / BM2;
    int wblk = (640 * 128 + 255) / 256;
    int nblk256 = (N + 255) / 256;

    // ---- CSR build (once) ----
    hipMemsetAsync(deg, 0, (size_t)N * 4, stream);
    degree_int_kernel<<<eblk, 256, 0, stream>>>(dst, deg, E);
    scan1_kernel<<<nb, 256, 0, stream>>>(deg, row_start, bsum, N);
    scan2_kernel<<<1, 256, 0, stream>>>(bsum, nb);
    scan3_kernel<<<nblk256, 256, 0, stream>>>(deg, bsum, row_start, inv, N, E);
    hipMemsetAsync(fill, 0, (size_t)N * 4, stream);
    fill_kernel<<<eblk, 256, 0, stream>>>(src, dst, row_start, fill, csr_src, csr_eid, E);
    coef_kernel<<<eblk, 256, 0, stream>>>(csr_eid, edge_type, edge_norm, att1, csr_coef, E);
    tobf_gather_kernel<<<gblk, 256, 0, stream>>>(entity, emb, xbf0, N);
    wprep_kernel<<<wblk, 256, 0, stream>>>(basis1, root1, Wt);

    // ---- layer 1: xbf0 -> xbf1 ----
    agg_kernel<<<ablk, 256, 0, stream>>>(row_start, deg, inv, csr_src, csr_coef, xbf0, Zbf, N);
    mfma_gemm_kernel<<<mblk, 512, 0, stream>>>(Zbf, xbf0, Wt, bias1, 0, 1, xbf1, nullptr, N);

    // ---- layer 2: xbf1 -> xbf0 (relu) ----
    agg_kernel<<<ablk, 256, 0, stream>>>(row_start, deg, inv, csr_src, csr_coef, xbf1, Zbf, N);
    mfma_gemm_kernel<<<mblk, 512, 0, stream>>>(Zbf, xbf1, Wt, bias1, 1, 1, xbf0, nullptr, N);

    // ---- layer 3: new coef (att2) + new weights; xbf0 -> out (fp32) ----
    coef_kernel<<<eblk, 256, 0, stream>>>(csr_eid, edge_type, edge_norm, att2, csr_coef, E);
    wprep_kernel<<<wblk, 256, 0, stream>>>(basis2, root2, Wt);
    agg_kernel<<<ablk, 256, 0, stream>>>(row_start, deg, inv, csr_src, csr_coef, xbf0, Zbf, N);
    mfma_gemm_kernel<<<mblk, 512, 0, stream>>>(Zbf, xbf0, Wt, bias2, 0, 0, nullptr, out, N);
}